// Round 15
// baseline (534.529 us; speedup 1.0000x reference)
//
#include <hip/hip_runtime.h>
#include <hip/hip_bf16.h>

#define NN 50000
#define EE 800000
#define DD 128

typedef __attribute__((ext_vector_type(8))) short short8;
typedef __attribute__((ext_vector_type(4))) float floatx4;

__device__ __forceinline__ unsigned short f2bf(float f) {   // RNE
    unsigned int x = __float_as_uint(f);
    unsigned int r = x + 0x7fffu + ((x >> 16) & 1u);
    return (unsigned short)(r >> 16);
}
__device__ __forceinline__ float2 bf2x2(unsigned int u) {   // [lo,hi] bf16 pair
    return make_float2(__uint_as_float(u << 16), __uint_as_float(u & 0xffff0000u));
}

// ---------------- degree (guarded) ----------------
__global__ void k_deg(const int* __restrict__ ei, int* __restrict__ deg) {
    int e = blockIdx.x * 256 + threadIdx.x;
    if (e < EE) {
        int d = ei[EE + e];
        if (d >= 0 && d < NN) atomicAdd(&deg[d], 1);
    }
}

// ---------------- CSR scan stage 1 ----------------
__global__ void k_scan_block(const int* __restrict__ deg, int* __restrict__ scanned,
                             int* __restrict__ blocksum) {
    __shared__ int lds[256];
    int t = threadIdx.x;
    int i = blockIdx.x * 256 + t;
    int v = (i < NN) ? deg[i] : 0;
    lds[t] = v;
    __syncthreads();
    for (int off = 1; off < 256; off <<= 1) {
        int add = (t >= off) ? lds[t - off] : 0;
        __syncthreads();
        lds[t] += add;
        __syncthreads();
    }
    if (i < NN) scanned[i] = lds[t];
    if (t == 255) blocksum[blockIdx.x] = lds[255];
}

// ---------------- CSR scan stage 2 (top-scan + final + dis + ELL pads) --------
__global__ void k_scan_final(const int* __restrict__ deg, const int* __restrict__ scanned,
                             const int* __restrict__ blocksum, int nb,
                             int* __restrict__ rowptr, int* __restrict__ cursor,
                             float* __restrict__ dis, int* __restrict__ ell) {
    __shared__ int lds[256];
    int t = threadIdx.x;
    int v = (t < nb) ? blocksum[t] : 0;
    lds[t] = v;
    __syncthreads();
    for (int off = 1; off < 256; off <<= 1) {
        int add = (t >= off) ? lds[t - off] : 0;
        __syncthreads();
        lds[t] += add;
        __syncthreads();
    }
    int boff = (blockIdx.x == 0) ? 0 : lds[blockIdx.x - 1];
    if (blockIdx.x == 0 && t == 0) rowptr[NN] = lds[nb - 1];
    int i = blockIdx.x * 256 + t;
    if (i < NN) {
        int d = deg[i];
        int rv = scanned[i] - d + boff;
        rowptr[i] = rv;
        cursor[i] = rv;
        dis[i] = rsqrtf((float)d + 1.0f);
        for (int slot = d; slot < 32; ++slot) ell[i * 32 + slot] = NN;  // pad -> zero row
    }
}

// csr + ELL real slots in one pass
__global__ void k_fill(const int* __restrict__ ei, const int* __restrict__ rowptr,
                       int* __restrict__ cursor, int* __restrict__ csr,
                       int* __restrict__ ell) {
    int e = blockIdx.x * 256 + threadIdx.x;
    if (e < EE) {
        int s = ei[e];
        int d = ei[EE + e];
        if ((unsigned)s < (unsigned)NN && (unsigned)d < (unsigned)NN) {
            int pos = atomicAdd(&cursor[d], 1);
            csr[pos] = s;
            int slot = pos - rowptr[d];
            if (slot < 32) ell[d * 32 + slot] = s;
        }
    }
}

// ---------------- W prep (fragment order) + zero HS pad row ----------------
__global__ void k_wprep(const float* __restrict__ conv_w, const float* __restrict__ mlp_w,
                        unsigned short* __restrict__ Wf, unsigned int* __restrict__ hsrow) {
    int g = blockIdx.x * 256 + threadIdx.x;
    if (g < 81920) {
        int m = g >> 14;
        int idx = g & 16383;
        int j  = idx & 7;
        int n  = (idx >> 3) & 15;
        int q  = (idx >> 7) & 3;
        int kk = (idx >> 9) & 3;
        int nt = (idx >> 11) & 1;
        int w  = (idx >> 12) & 3;
        int k = kk * 32 + q * 8 + j;
        int c = w * 32 + nt * 16 + n;
        const float* src = (m < 3) ? (conv_w + m * 16384) : (mlp_w + (m - 3) * 16384);
        Wf[g] = f2bf(src[k * 128 + c]);
    } else if (g - 81920 < 64) {
        hsrow[g - 81920] = 0u;                  // zero pad row HS[NN]
    }
}

// ---------------- conv MFMA GEMM: HS = pro(IN) @ W * dis -> bf16 ----------------
// PRO 0: IN fp32, no BN (layer 0).  PRO 1: IN bf16, BN+relu while staging.
#define LSTR 136
template<int PRO>
__global__ __launch_bounds__(256) void k_gemm_conv(const void* __restrict__ INv,
                                                   const unsigned short* __restrict__ Wf,
                                                   const float* __restrict__ dis,
                                                   const float* __restrict__ cs,
                                                   const float* __restrict__ css,
                                                   const float* __restrict__ gamma,
                                                   const float* __restrict__ beta,
                                                   unsigned short* __restrict__ OUT) {
    __shared__ unsigned short Al[64 * LSTR];
    __shared__ float bnscL[128], bnshL[128];
    const int tid = threadIdx.x;
    const int lane = tid & 63;
    const int w = tid >> 6;
    const int row0 = blockIdx.x * 64;

    if (PRO) {
        if (tid < 128) {
            const float invn = 1.f / (float)NN;
            float mean = cs[tid] * invn;
            float var = css[tid] * invn - mean * mean;
            float sc = gamma[tid] * rsqrtf(fmaxf(var, 0.f) + 1e-5f);
            bnscL[tid] = sc;
            bnshL[tid] = beta[tid] - mean * sc;
        }
        __syncthreads();
    }

    short8 bf[2][4];
    {
        const uint4* Wq = (const uint4*)Wf;
#pragma unroll
        for (int nt = 0; nt < 2; ++nt)
#pragma unroll
            for (int kk = 0; kk < 4; ++kk) {
                uint4 u = Wq[((w * 2 + nt) * 4 + kk) * 64 + lane];
                bf[nt][kk] = *(short8*)&u;
            }
    }

    {
        int r = tid >> 2, kq = (tid & 3) * 32;
        int gr = row0 + r;
        unsigned short tmp[32];
        if (PRO == 0) {
            const float* IN = (const float*)INv;
#pragma unroll
            for (int i = 0; i < 8; ++i) {
                float4 v = make_float4(0.f, 0.f, 0.f, 0.f);
                if (gr < NN) v = *(const float4*)&IN[(size_t)gr * DD + kq + i * 4];
                tmp[i * 4 + 0] = f2bf(v.x); tmp[i * 4 + 1] = f2bf(v.y);
                tmp[i * 4 + 2] = f2bf(v.z); tmp[i * 4 + 3] = f2bf(v.w);
            }
        } else {
            const unsigned int* inu = (const unsigned int*)INv;
#pragma unroll
            for (int i = 0; i < 4; ++i) {
                uint4 u = make_uint4(0u, 0u, 0u, 0u);
                if (gr < NN) u = *(const uint4*)&inu[(size_t)gr * 64 + (kq >> 1) + i * 4];
                float2 p0 = bf2x2(u.x), p1 = bf2x2(u.y), p2 = bf2x2(u.z), p3 = bf2x2(u.w);
                float vv[8] = {p0.x, p0.y, p1.x, p1.y, p2.x, p2.y, p3.x, p3.y};
#pragma unroll
                for (int j = 0; j < 8; ++j) {
                    float t2 = fmaf(vv[j], bnscL[kq + i * 8 + j], bnshL[kq + i * 8 + j]);
                    tmp[i * 8 + j] = f2bf(fmaxf(t2, 0.f));
                }
            }
        }
#pragma unroll
        for (int j = 0; j < 4; ++j)
            *(uint4*)&Al[r * LSTR + kq + j * 8] = ((uint4*)tmp)[j];
    }
    __syncthreads();

    const int n = lane & 15, q = lane >> 4;
    floatx4 acc[4][2];
#pragma unroll
    for (int mt = 0; mt < 4; ++mt)
#pragma unroll
        for (int nt = 0; nt < 2; ++nt)
            acc[mt][nt] = (floatx4){0.f, 0.f, 0.f, 0.f};

#pragma unroll
    for (int kk = 0; kk < 4; ++kk) {
        int ko = kk * 32 + q * 8;
#pragma unroll
        for (int mt = 0; mt < 4; ++mt) {
            short8 a = *(const short8*)&Al[(mt * 16 + n) * LSTR + ko];
            acc[mt][0] = __builtin_amdgcn_mfma_f32_16x16x32_bf16(a, bf[0][kk], acc[mt][0], 0, 0, 0);
            acc[mt][1] = __builtin_amdgcn_mfma_f32_16x16x32_bf16(a, bf[1][kk], acc[mt][1], 0, 0, 0);
        }
    }

#pragma unroll
    for (int mt = 0; mt < 4; ++mt) {
#pragma unroll
        for (int reg = 0; reg < 4; ++reg) {
            int r = row0 + mt * 16 + q * 4 + reg;
            if (r < NN) {
                float sc = dis[r];
                OUT[(size_t)r * DD + w * 32 + n]      = f2bf(acc[mt][0][reg] * sc);
                OUT[(size_t)r * DD + w * 32 + 16 + n] = f2bf(acc[mt][1][reg] * sc);
            }
        }
    }
}

// ---------------- fused MLP + head (bf16 input, BN no relu) ----------------
__global__ __launch_bounds__(256) void k_mlp_head(const unsigned int* __restrict__ INu,
                                                  const unsigned short* __restrict__ Wf4,
                                                  const unsigned short* __restrict__ Wf5,
                                                  const float* __restrict__ b4,
                                                  const float* __restrict__ b5,
                                                  const float* __restrict__ cs,
                                                  const float* __restrict__ css,
                                                  const float* __restrict__ gamma,
                                                  const float* __restrict__ beta,
                                                  const float* __restrict__ ow,
                                                  const float* __restrict__ ob,
                                                  float* __restrict__ out) {
    __shared__ unsigned short Al[64 * LSTR];
    __shared__ float bnscL[128], bnshL[128];
    __shared__ float redH[4][64];
    const int tid = threadIdx.x;
    const int lane = tid & 63;
    const int w = tid >> 6;
    const int row0 = blockIdx.x * 64;
    const int n = lane & 15, q = lane >> 4;

    if (tid < 128) {
        const float invn = 1.f / (float)NN;
        float mean = cs[tid] * invn;
        float var = css[tid] * invn - mean * mean;
        float sc = gamma[tid] * rsqrtf(fmaxf(var, 0.f) + 1e-5f);
        bnscL[tid] = sc;
        bnshL[tid] = beta[tid] - mean * sc;
    }
    __syncthreads();

    {
        int r = tid >> 2, kq = (tid & 3) * 32;
        int gr = row0 + r;
        unsigned short tmp[32];
#pragma unroll
        for (int i = 0; i < 4; ++i) {
            uint4 u = make_uint4(0u, 0u, 0u, 0u);
            if (gr < NN) u = *(const uint4*)&INu[(size_t)gr * 64 + (kq >> 1) + i * 4];
            float2 p0 = bf2x2(u.x), p1 = bf2x2(u.y), p2 = bf2x2(u.z), p3 = bf2x2(u.w);
            float vv[8] = {p0.x, p0.y, p1.x, p1.y, p2.x, p2.y, p3.x, p3.y};
#pragma unroll
            for (int j = 0; j < 8; ++j) {
                float t2 = fmaf(vv[j], bnscL[kq + i * 8 + j], bnshL[kq + i * 8 + j]);
                tmp[i * 8 + j] = f2bf(t2);
            }
        }
#pragma unroll
        for (int j = 0; j < 4; ++j)
            *(uint4*)&Al[r * LSTR + kq + j * 8] = ((uint4*)tmp)[j];
    }
    __syncthreads();

    floatx4 acc[4][2];
#pragma unroll
    for (int mt = 0; mt < 4; ++mt)
#pragma unroll
        for (int nt = 0; nt < 2; ++nt)
            acc[mt][nt] = (floatx4){0.f, 0.f, 0.f, 0.f};
    {
        const uint4* Wq = (const uint4*)Wf4;
#pragma unroll
        for (int kk = 0; kk < 4; ++kk) {
            uint4 u0 = Wq[((w * 2 + 0) * 4 + kk) * 64 + lane];
            uint4 u1 = Wq[((w * 2 + 1) * 4 + kk) * 64 + lane];
            int ko = kk * 32 + q * 8;
#pragma unroll
            for (int mt = 0; mt < 4; ++mt) {
                short8 a = *(const short8*)&Al[(mt * 16 + n) * LSTR + ko];
                acc[mt][0] = __builtin_amdgcn_mfma_f32_16x16x32_bf16(a, *(short8*)&u0, acc[mt][0], 0, 0, 0);
                acc[mt][1] = __builtin_amdgcn_mfma_f32_16x16x32_bf16(a, *(short8*)&u1, acc[mt][1], 0, 0, 0);
            }
        }
    }
    __syncthreads();

    {
        float b0c = b4[w * 32 + n], b1c = b4[w * 32 + 16 + n];
#pragma unroll
        for (int mt = 0; mt < 4; ++mt) {
#pragma unroll
            for (int reg = 0; reg < 4; ++reg) {
                int r = mt * 16 + q * 4 + reg;
                Al[r * LSTR + w * 32 + n]      = f2bf(fmaxf(acc[mt][0][reg] + b0c, 0.f));
                Al[r * LSTR + w * 32 + 16 + n] = f2bf(fmaxf(acc[mt][1][reg] + b1c, 0.f));
            }
        }
    }
    __syncthreads();

#pragma unroll
    for (int mt = 0; mt < 4; ++mt)
#pragma unroll
        for (int nt = 0; nt < 2; ++nt)
            acc[mt][nt] = (floatx4){0.f, 0.f, 0.f, 0.f};
    {
        const uint4* Wq = (const uint4*)Wf5;
#pragma unroll
        for (int kk = 0; kk < 4; ++kk) {
            uint4 u0 = Wq[((w * 2 + 0) * 4 + kk) * 64 + lane];
            uint4 u1 = Wq[((w * 2 + 1) * 4 + kk) * 64 + lane];
            int ko = kk * 32 + q * 8;
#pragma unroll
            for (int mt = 0; mt < 4; ++mt) {
                short8 a = *(const short8*)&Al[(mt * 16 + n) * LSTR + ko];
                acc[mt][0] = __builtin_amdgcn_mfma_f32_16x16x32_bf16(a, *(short8*)&u0, acc[mt][0], 0, 0, 0);
                acc[mt][1] = __builtin_amdgcn_mfma_f32_16x16x32_bf16(a, *(short8*)&u1, acc[mt][1], 0, 0, 0);
            }
        }
    }
    {
        float b0c = b5[w * 32 + n], b1c = b5[w * 32 + 16 + n];
        float w0c = ow[w * 32 + n], w1c = ow[w * 32 + 16 + n];
#pragma unroll
        for (int mt = 0; mt < 4; ++mt) {
#pragma unroll
            for (int reg = 0; reg < 4; ++reg) {
                float h0 = fmaxf(acc[mt][0][reg] + b0c, 0.f);
                float h1 = fmaxf(acc[mt][1][reg] + b1c, 0.f);
                float p = fmaf(h0, w0c, h1 * w1c);
                p += __shfl_xor(p, 1);
                p += __shfl_xor(p, 2);
                p += __shfl_xor(p, 4);
                p += __shfl_xor(p, 8);
                if (n == 0) redH[w][mt * 16 + q * 4 + reg] = p;
            }
        }
        __syncthreads();
        if (tid < 64) {
            int r = row0 + tid;
            if (r < NN) {
                float z = (redH[0][tid] + redH[1][tid]) + (redH[2][tid] + redH[3][tid]) + ob[0];
                out[r] = 1.f / (1.f + expf(-z));
            }
        }
    }
}
#undef LSTR

// ---------------- gather: ELL fast path, dynamic row queue, bf16 out ----------
template<int RELU>
__global__ __launch_bounds__(256) void k_gather(const int* __restrict__ rowptr,
                                                const int* __restrict__ csr,
                                                const int* __restrict__ ell,
                                                const uint4* __restrict__ HSq,
                                                const float* __restrict__ dis,
                                                const float* __restrict__ bias,
                                                unsigned short* __restrict__ OUT,
                                                float* __restrict__ colsum,
                                                float* __restrict__ colsumsq,
                                                int* __restrict__ wctr) {
    const int tid = threadIdx.x;
    const int lane = tid & 63;
    const int wid = tid >> 6;
    const int c = lane & 15;
    const int jj = lane >> 4;

    float4 bia0 = ((const float4*)bias)[2 * c];
    float4 bia1 = ((const float4*)bias)[2 * c + 1];
    float sum[8], sq[8];
#pragma unroll
    for (int t = 0; t < 8; ++t) { sum[t] = 0.f; sq[t] = 0.f; }

    __shared__ int baseS;
    for (;;) {
        __syncthreads();
        if (tid == 0) baseS = atomicAdd(wctr, 16);
        __syncthreads();
        int base = baseS;
        if (base >= NN) break;
        int r0 = base + wid * 4;
        int r1 = min(r0 + 4, NN);
        for (int r = r0; r < r1; ++r) {
            int beg = rowptr[r], end = rowptr[r + 1];
            int d = end - beg;
            float a[8];
#pragma unroll
            for (int t = 0; t < 8; ++t) a[t] = 0.f;

            if (jj == 0) {   // self loop
                uint4 u = HSq[(size_t)r * 16 + c];
                float2 p0 = bf2x2(u.x), p1 = bf2x2(u.y), p2 = bf2x2(u.z), p3 = bf2x2(u.w);
                a[0] += p0.x; a[1] += p0.y; a[2] += p1.x; a[3] += p1.y;
                a[4] += p2.x; a[5] += p2.y; a[6] += p3.x; a[7] += p3.y;
            }

            if (d <= 32) {
                const int4* e4 = (const int4*)(ell + r * 32);
                int4 ia = e4[jj];
                int4 ib = e4[jj + 4];
                uint4 v0 = HSq[(size_t)ia.x * 16 + c];
                uint4 v1 = HSq[(size_t)ia.y * 16 + c];
                uint4 v2 = HSq[(size_t)ia.z * 16 + c];
                uint4 v3 = HSq[(size_t)ia.w * 16 + c];
                uint4 v4 = HSq[(size_t)ib.x * 16 + c];
                uint4 v5 = HSq[(size_t)ib.y * 16 + c];
                uint4 v6 = HSq[(size_t)ib.z * 16 + c];
                uint4 v7 = HSq[(size_t)ib.w * 16 + c];
                uint4 vs[8] = {v0, v1, v2, v3, v4, v5, v6, v7};
#pragma unroll
                for (int t = 0; t < 8; ++t) {
                    float2 p0 = bf2x2(vs[t].x), p1 = bf2x2(vs[t].y);
                    float2 p2 = bf2x2(vs[t].z), p3 = bf2x2(vs[t].w);
                    a[0] += p0.x; a[1] += p0.y; a[2] += p1.x; a[3] += p1.y;
                    a[4] += p2.x; a[5] += p2.y; a[6] += p3.x; a[7] += p3.y;
                }
            } else {
                int e1 = end - 1;
                for (int j = beg; j < end; j += 16) {
                    int i0 = j + jj, i1 = j + 4 + jj, i2 = j + 8 + jj, i3 = j + 12 + jj;
                    int s0 = csr[min(i0, e1)];
                    int s1 = csr[min(i1, e1)];
                    int s2 = csr[min(i2, e1)];
                    int s3 = csr[min(i3, e1)];
                    uint4 v0 = HSq[(size_t)s0 * 16 + c];
                    uint4 v1 = HSq[(size_t)s1 * 16 + c];
                    uint4 v2 = HSq[(size_t)s2 * 16 + c];
                    uint4 v3 = HSq[(size_t)s3 * 16 + c];
                    if (i0 < end) {
                        float2 p0 = bf2x2(v0.x), p1 = bf2x2(v0.y), p2 = bf2x2(v0.z), p3 = bf2x2(v0.w);
                        a[0] += p0.x; a[1] += p0.y; a[2] += p1.x; a[3] += p1.y;
                        a[4] += p2.x; a[5] += p2.y; a[6] += p3.x; a[7] += p3.y;
                    }
                    if (i1 < end) {
                        float2 p0 = bf2x2(v1.x), p1 = bf2x2(v1.y), p2 = bf2x2(v1.z), p3 = bf2x2(v1.w);
                        a[0] += p0.x; a[1] += p0.y; a[2] += p1.x; a[3] += p1.y;
                        a[4] += p2.x; a[5] += p2.y; a[6] += p3.x; a[7] += p3.y;
                    }
                    if (i2 < end) {
                        float2 p0 = bf2x2(v2.x), p1 = bf2x2(v2.y), p2 = bf2x2(v2.z), p3 = bf2x2(v2.w);
                        a[0] += p0.x; a[1] += p0.y; a[2] += p1.x; a[3] += p1.y;
                        a[4] += p2.x; a[5] += p2.y; a[6] += p3.x; a[7] += p3.y;
                    }
                    if (i3 < end) {
                        float2 p0 = bf2x2(v3.x), p1 = bf2x2(v3.y), p2 = bf2x2(v3.z), p3 = bf2x2(v3.w);
                        a[0] += p0.x; a[1] += p0.y; a[2] += p1.x; a[3] += p1.y;
                        a[4] += p2.x; a[5] += p2.y; a[6] += p3.x; a[7] += p3.y;
                    }
                }
            }

#pragma unroll
            for (int t = 0; t < 8; ++t) {
                a[t] += __shfl_xor(a[t], 16);
                a[t] += __shfl_xor(a[t], 32);
            }

            if (jj == 0) {
                float dr = dis[r];
                float v[8];
                v[0] = fmaf(dr, a[0], bia0.x); v[1] = fmaf(dr, a[1], bia0.y);
                v[2] = fmaf(dr, a[2], bia0.z); v[3] = fmaf(dr, a[3], bia0.w);
                v[4] = fmaf(dr, a[4], bia1.x); v[5] = fmaf(dr, a[5], bia1.y);
                v[6] = fmaf(dr, a[6], bia1.z); v[7] = fmaf(dr, a[7], bia1.w);
                if (RELU) {
#pragma unroll
                    for (int t = 0; t < 8; ++t) v[t] = fmaxf(v[t], 0.f);
                }
                unsigned int p[4];
#pragma unroll
                for (int t = 0; t < 4; ++t)
                    p[t] = (unsigned int)f2bf(v[2 * t]) | ((unsigned int)f2bf(v[2 * t + 1]) << 16);
                *(uint4*)&OUT[(size_t)r * DD + c * 8] = make_uint4(p[0], p[1], p[2], p[3]);
#pragma unroll
                for (int t = 0; t < 8; ++t) { sum[t] += v[t]; sq[t] += v[t] * v[t]; }
            }
        }
    }

    __shared__ float redS[4][16][8];
    __shared__ float redQ[4][16][8];
    if (jj == 0) {
#pragma unroll
        for (int t = 0; t < 8; ++t) { redS[wid][c][t] = sum[t]; redQ[wid][c][t] = sq[t]; }
    }
    __syncthreads();
    if (tid < 128) {
        int ci = tid >> 3, ct = tid & 7;
        float S = (redS[0][ci][ct] + redS[1][ci][ct]) + (redS[2][ci][ct] + redS[3][ci][ct]);
        float Q = (redQ[0][ci][ct] + redQ[1][ci][ct]) + (redQ[2][ci][ct] + redQ[3][ci][ct]);
        atomicAdd(&colsum[tid], S);
        atomicAdd(&colsumsq[tid], Q);
    }
}

extern "C" void kernel_launch(void* const* d_in, const int* in_sizes, int n_in,
                              void* d_out, int out_size, void* d_ws, size_t ws_size,
                              hipStream_t stream) {
    const float* x      = (const float*)d_in[0];
    const int*   ei     = (const int*)d_in[1];
    const float* conv_w = (const float*)d_in[2];
    const float* conv_b = (const float*)d_in[3];
    const float* bn_g   = (const float*)d_in[4];
    const float* bn_b   = (const float*)d_in[5];
    const float* mlp_w  = (const float*)d_in[6];
    const float* mlp_b  = (const float*)d_in[7];
    const float* out_w  = (const float*)d_in[8];
    const float* out_b  = (const float*)d_in[9];
    float* out = (float*)d_out;

    const size_t ND4 = (size_t)NN * DD * 4;   // 25,600,000 B
    char* ws = (char*)d_ws;
    size_t off = 0;
    unsigned short* B0 = (unsigned short*)(ws + off); off += ND4 / 2;        // bf16 features
    unsigned short* B1b = (unsigned short*)(ws + off); off += ND4 / 2 + 256; // bf16 HS + pad row
    int*   deg     = (int*)  (ws + off); off += 204800;             // zeroed region start
    float* cs3     = (float*)(ws + off); off += 3 * 512;
    float* css3    = (float*)(ws + off); off += 3 * 512;
    int*   wctr    = (int*)  (ws + off); off += 64;                 // zeroed region end
    float* dis     = (float*)(ws + off); off += 204800;
    int*   rowptr  = (int*)  (ws + off); off += 204804 + 60;
    int*   cursor  = (int*)  (ws + off); off += 204800;
    int*   bsum    = (int*)  (ws + off); off += 1024;
    unsigned short* Wfb = (unsigned short*)(ws + off); off += 5 * 16384 * 2;
    int*   csr     = (int*)  (ws + off); off += (size_t)EE * 4;
    int*   ell     = (int*)  (ws + off); off += (size_t)NN * 32 * 4;  // 6.4MB
    // total ≈ 36.5 MB

    const int gemm_grid = (NN + 63) / 64;     // 782
    const int nscan = (NN + 255) / 256;       // 196
    const int gather_grid = 2048;             // 8192 waves

    hipMemsetAsync(deg, 0, 204800 + 6 * 512 + 64, stream);

    k_deg<<<(EE + 255) / 256, 256, 0, stream>>>(ei, deg);
    k_scan_block<<<nscan, 256, 0, stream>>>(deg, cursor, bsum);
    k_scan_final<<<nscan, 256, 0, stream>>>(deg, cursor, bsum, nscan, rowptr, cursor, dis, ell);
    k_fill<<<(EE + 255) / 256, 256, 0, stream>>>(ei, rowptr, cursor, csr, ell);
    k_wprep<<<321, 256, 0, stream>>>(conv_w, mlp_w, Wfb, (unsigned int*)(B1b + (size_t)NN * DD));

    // ---- layer 0 ----
    k_gemm_conv<0><<<gemm_grid, 256, 0, stream>>>(x, Wfb, dis,
        nullptr, nullptr, nullptr, nullptr, B1b);
    k_gather<0><<<gather_grid, 256, 0, stream>>>(rowptr, csr, ell, (const uint4*)B1b, dis, conv_b, B0, cs3, css3, wctr);

    // ---- layer 1 ----
    k_gemm_conv<1><<<gemm_grid, 256, 0, stream>>>(B0, Wfb + 16384, dis,
        cs3, css3, bn_g, bn_b, B1b);
    k_gather<0><<<gather_grid, 256, 0, stream>>>(rowptr, csr, ell, (const uint4*)B1b, dis, conv_b + DD, B0, cs3 + 128, css3 + 128, wctr + 1);

    // ---- layer 2 ----
    k_gemm_conv<1><<<gemm_grid, 256, 0, stream>>>(B0, Wfb + 2 * 16384, dis,
        cs3 + 128, css3 + 128, bn_g + DD, bn_b + DD, B1b);
    k_gather<1><<<gather_grid, 256, 0, stream>>>(rowptr, csr, ell, (const uint4*)B1b, dis, conv_b + 2 * DD, B0, cs3 + 256, css3 + 256, wctr + 2);

    // ---- fused MLP + head ----
    k_mlp_head<<<gemm_grid, 256, 0, stream>>>((const unsigned int*)B0, Wfb + 3 * 16384, Wfb + 4 * 16384,
        mlp_b, mlp_b + DD, cs3 + 256, css3 + 256, bn_g + DD, bn_b + DD, out_w, out_b, out);
}

// Round 16
// 449.898 us; speedup vs baseline: 1.1881x; 1.1881x over previous
//
#include <hip/hip_runtime.h>
#include <hip/hip_bf16.h>

#define NN 50000
#define EE 800000
#define DD 128

typedef __attribute__((ext_vector_type(8))) short short8;
typedef __attribute__((ext_vector_type(4))) float floatx4;

__device__ __forceinline__ unsigned short f2bf(float f) {   // RNE
    unsigned int x = __float_as_uint(f);
    unsigned int r = x + 0x7fffu + ((x >> 16) & 1u);
    return (unsigned short)(r >> 16);
}
__device__ __forceinline__ float2 bf2x2(unsigned int u) {   // [lo,hi] bf16 pair
    return make_float2(__uint_as_float(u << 16), __uint_as_float(u & 0xffff0000u));
}

// ---------------- degree (guarded) ----------------
__global__ void k_deg(const int* __restrict__ ei, int* __restrict__ deg) {
    int e = blockIdx.x * 256 + threadIdx.x;
    if (e < EE) {
        int d = ei[EE + e];
        if (d >= 0 && d < NN) atomicAdd(&deg[d], 1);
    }
}

// ---------------- CSR scan stage 1 ----------------
__global__ void k_scan_block(const int* __restrict__ deg, int* __restrict__ scanned,
                             int* __restrict__ blocksum) {
    __shared__ int lds[256];
    int t = threadIdx.x;
    int i = blockIdx.x * 256 + t;
    int v = (i < NN) ? deg[i] : 0;
    lds[t] = v;
    __syncthreads();
    for (int off = 1; off < 256; off <<= 1) {
        int add = (t >= off) ? lds[t - off] : 0;
        __syncthreads();
        lds[t] += add;
        __syncthreads();
    }
    if (i < NN) scanned[i] = lds[t];
    if (t == 255) blocksum[blockIdx.x] = lds[255];
}

// ---------------- CSR scan stage 2 (top-scan + final + dis + ELL pads) --------
__global__ void k_scan_final(const int* __restrict__ deg, const int* __restrict__ scanned,
                             const int* __restrict__ blocksum, int nb,
                             int* __restrict__ rowptr, int* __restrict__ cursor,
                             float* __restrict__ dis, int* __restrict__ ell) {
    __shared__ int lds[256];
    int t = threadIdx.x;
    int v = (t < nb) ? blocksum[t] : 0;
    lds[t] = v;
    __syncthreads();
    for (int off = 1; off < 256; off <<= 1) {
        int add = (t >= off) ? lds[t - off] : 0;
        __syncthreads();
        lds[t] += add;
        __syncthreads();
    }
    int boff = (blockIdx.x == 0) ? 0 : lds[blockIdx.x - 1];
    if (blockIdx.x == 0 && t == 0) rowptr[NN] = lds[nb - 1];
    int i = blockIdx.x * 256 + t;
    if (i < NN) {
        int d = deg[i];
        int rv = scanned[i] - d + boff;
        rowptr[i] = rv;
        cursor[i] = rv;
        dis[i] = rsqrtf((float)d + 1.0f);
        for (int slot = d; slot < 32; ++slot) ell[i * 32 + slot] = NN;  // pad -> zero row
    }
}

// csr + ELL real slots in one pass
__global__ void k_fill(const int* __restrict__ ei, const int* __restrict__ rowptr,
                       int* __restrict__ cursor, int* __restrict__ csr,
                       int* __restrict__ ell) {
    int e = blockIdx.x * 256 + threadIdx.x;
    if (e < EE) {
        int s = ei[e];
        int d = ei[EE + e];
        if ((unsigned)s < (unsigned)NN && (unsigned)d < (unsigned)NN) {
            int pos = atomicAdd(&cursor[d], 1);
            csr[pos] = s;
            int slot = pos - rowptr[d];
            if (slot < 32) ell[d * 32 + slot] = s;
        }
    }
}

// ---------------- W prep (fragment order) + zero HS pad row ----------------
__global__ void k_wprep(const float* __restrict__ conv_w, const float* __restrict__ mlp_w,
                        unsigned short* __restrict__ Wf, unsigned int* __restrict__ hsrow) {
    int g = blockIdx.x * 256 + threadIdx.x;
    if (g < 81920) {
        int m = g >> 14;
        int idx = g & 16383;
        int j  = idx & 7;
        int n  = (idx >> 3) & 15;
        int q  = (idx >> 7) & 3;
        int kk = (idx >> 9) & 3;
        int nt = (idx >> 11) & 1;
        int w  = (idx >> 12) & 3;
        int k = kk * 32 + q * 8 + j;
        int c = w * 32 + nt * 16 + n;
        const float* src = (m < 3) ? (conv_w + m * 16384) : (mlp_w + (m - 3) * 16384);
        Wf[g] = f2bf(src[k * 128 + c]);
    } else if (g - 81920 < 64) {
        hsrow[g - 81920] = 0u;                  // zero pad row HS[NN]
    }
}

// ---------------- conv MFMA GEMM: HS = pro(IN) @ W * dis -> bf16 ----------------
// PRO 0: IN fp32, no BN (layer 0).  PRO 1: IN bf16, BN+relu while staging.
#define LSTR 136
template<int PRO>
__global__ __launch_bounds__(256) void k_gemm_conv(const void* __restrict__ INv,
                                                   const unsigned short* __restrict__ Wf,
                                                   const float* __restrict__ dis,
                                                   const float* __restrict__ cs,
                                                   const float* __restrict__ css,
                                                   const float* __restrict__ gamma,
                                                   const float* __restrict__ beta,
                                                   unsigned short* __restrict__ OUT) {
    __shared__ unsigned short Al[64 * LSTR];
    __shared__ float bnscL[128], bnshL[128];
    const int tid = threadIdx.x;
    const int lane = tid & 63;
    const int w = tid >> 6;
    const int row0 = blockIdx.x * 64;

    if (PRO) {
        if (tid < 128) {
            const float invn = 1.f / (float)NN;
            float mean = cs[tid] * invn;
            float var = css[tid] * invn - mean * mean;
            float sc = gamma[tid] * rsqrtf(fmaxf(var, 0.f) + 1e-5f);
            bnscL[tid] = sc;
            bnshL[tid] = beta[tid] - mean * sc;
        }
        __syncthreads();
    }

    short8 bf[2][4];
    {
        const uint4* Wq = (const uint4*)Wf;
#pragma unroll
        for (int nt = 0; nt < 2; ++nt)
#pragma unroll
            for (int kk = 0; kk < 4; ++kk) {
                uint4 u = Wq[((w * 2 + nt) * 4 + kk) * 64 + lane];
                bf[nt][kk] = *(short8*)&u;
            }
    }

    {
        int r = tid >> 2, kq = (tid & 3) * 32;
        int gr = row0 + r;
        unsigned short tmp[32];
        if (PRO == 0) {
            const float* IN = (const float*)INv;
#pragma unroll
            for (int i = 0; i < 8; ++i) {
                float4 v = make_float4(0.f, 0.f, 0.f, 0.f);
                if (gr < NN) v = *(const float4*)&IN[(size_t)gr * DD + kq + i * 4];
                tmp[i * 4 + 0] = f2bf(v.x); tmp[i * 4 + 1] = f2bf(v.y);
                tmp[i * 4 + 2] = f2bf(v.z); tmp[i * 4 + 3] = f2bf(v.w);
            }
        } else {
            const unsigned int* inu = (const unsigned int*)INv;
#pragma unroll
            for (int i = 0; i < 4; ++i) {
                uint4 u = make_uint4(0u, 0u, 0u, 0u);
                if (gr < NN) u = *(const uint4*)&inu[(size_t)gr * 64 + (kq >> 1) + i * 4];
                float2 p0 = bf2x2(u.x), p1 = bf2x2(u.y), p2 = bf2x2(u.z), p3 = bf2x2(u.w);
                float vv[8] = {p0.x, p0.y, p1.x, p1.y, p2.x, p2.y, p3.x, p3.y};
#pragma unroll
                for (int j = 0; j < 8; ++j) {
                    float t2 = fmaf(vv[j], bnscL[kq + i * 8 + j], bnshL[kq + i * 8 + j]);
                    tmp[i * 8 + j] = f2bf(fmaxf(t2, 0.f));
                }
            }
        }
#pragma unroll
        for (int j = 0; j < 4; ++j)
            *(uint4*)&Al[r * LSTR + kq + j * 8] = ((uint4*)tmp)[j];
    }
    __syncthreads();

    const int n = lane & 15, q = lane >> 4;
    floatx4 acc[4][2];
#pragma unroll
    for (int mt = 0; mt < 4; ++mt)
#pragma unroll
        for (int nt = 0; nt < 2; ++nt)
            acc[mt][nt] = (floatx4){0.f, 0.f, 0.f, 0.f};

#pragma unroll
    for (int kk = 0; kk < 4; ++kk) {
        int ko = kk * 32 + q * 8;
#pragma unroll
        for (int mt = 0; mt < 4; ++mt) {
            short8 a = *(const short8*)&Al[(mt * 16 + n) * LSTR + ko];
            acc[mt][0] = __builtin_amdgcn_mfma_f32_16x16x32_bf16(a, bf[0][kk], acc[mt][0], 0, 0, 0);
            acc[mt][1] = __builtin_amdgcn_mfma_f32_16x16x32_bf16(a, bf[1][kk], acc[mt][1], 0, 0, 0);
        }
    }

#pragma unroll
    for (int mt = 0; mt < 4; ++mt) {
#pragma unroll
        for (int reg = 0; reg < 4; ++reg) {
            int r = row0 + mt * 16 + q * 4 + reg;
            if (r < NN) {
                float sc = dis[r];
                OUT[(size_t)r * DD + w * 32 + n]      = f2bf(acc[mt][0][reg] * sc);
                OUT[(size_t)r * DD + w * 32 + 16 + n] = f2bf(acc[mt][1][reg] * sc);
            }
        }
    }
}

// ---------------- fused MLP + head (bf16 input, BN no relu) ----------------
__global__ __launch_bounds__(256) void k_mlp_head(const unsigned int* __restrict__ INu,
                                                  const unsigned short* __restrict__ Wf4,
                                                  const unsigned short* __restrict__ Wf5,
                                                  const float* __restrict__ b4,
                                                  const float* __restrict__ b5,
                                                  const float* __restrict__ cs,
                                                  const float* __restrict__ css,
                                                  const float* __restrict__ gamma,
                                                  const float* __restrict__ beta,
                                                  const float* __restrict__ ow,
                                                  const float* __restrict__ ob,
                                                  float* __restrict__ out) {
    __shared__ unsigned short Al[64 * LSTR];
    __shared__ float bnscL[128], bnshL[128];
    __shared__ float redH[4][64];
    const int tid = threadIdx.x;
    const int lane = tid & 63;
    const int w = tid >> 6;
    const int row0 = blockIdx.x * 64;
    const int n = lane & 15, q = lane >> 4;

    if (tid < 128) {
        const float invn = 1.f / (float)NN;
        float mean = cs[tid] * invn;
        float var = css[tid] * invn - mean * mean;
        float sc = gamma[tid] * rsqrtf(fmaxf(var, 0.f) + 1e-5f);
        bnscL[tid] = sc;
        bnshL[tid] = beta[tid] - mean * sc;
    }
    __syncthreads();

    {
        int r = tid >> 2, kq = (tid & 3) * 32;
        int gr = row0 + r;
        unsigned short tmp[32];
#pragma unroll
        for (int i = 0; i < 4; ++i) {
            uint4 u = make_uint4(0u, 0u, 0u, 0u);
            if (gr < NN) u = *(const uint4*)&INu[(size_t)gr * 64 + (kq >> 1) + i * 4];
            float2 p0 = bf2x2(u.x), p1 = bf2x2(u.y), p2 = bf2x2(u.z), p3 = bf2x2(u.w);
            float vv[8] = {p0.x, p0.y, p1.x, p1.y, p2.x, p2.y, p3.x, p3.y};
#pragma unroll
            for (int j = 0; j < 8; ++j) {
                float t2 = fmaf(vv[j], bnscL[kq + i * 8 + j], bnshL[kq + i * 8 + j]);
                tmp[i * 8 + j] = f2bf(t2);
            }
        }
#pragma unroll
        for (int j = 0; j < 4; ++j)
            *(uint4*)&Al[r * LSTR + kq + j * 8] = ((uint4*)tmp)[j];
    }
    __syncthreads();

    floatx4 acc[4][2];
#pragma unroll
    for (int mt = 0; mt < 4; ++mt)
#pragma unroll
        for (int nt = 0; nt < 2; ++nt)
            acc[mt][nt] = (floatx4){0.f, 0.f, 0.f, 0.f};
    {
        const uint4* Wq = (const uint4*)Wf4;
#pragma unroll
        for (int kk = 0; kk < 4; ++kk) {
            uint4 u0 = Wq[((w * 2 + 0) * 4 + kk) * 64 + lane];
            uint4 u1 = Wq[((w * 2 + 1) * 4 + kk) * 64 + lane];
            int ko = kk * 32 + q * 8;
#pragma unroll
            for (int mt = 0; mt < 4; ++mt) {
                short8 a = *(const short8*)&Al[(mt * 16 + n) * LSTR + ko];
                acc[mt][0] = __builtin_amdgcn_mfma_f32_16x16x32_bf16(a, *(short8*)&u0, acc[mt][0], 0, 0, 0);
                acc[mt][1] = __builtin_amdgcn_mfma_f32_16x16x32_bf16(a, *(short8*)&u1, acc[mt][1], 0, 0, 0);
            }
        }
    }
    __syncthreads();

    {
        float b0c = b4[w * 32 + n], b1c = b4[w * 32 + 16 + n];
#pragma unroll
        for (int mt = 0; mt < 4; ++mt) {
#pragma unroll
            for (int reg = 0; reg < 4; ++reg) {
                int r = mt * 16 + q * 4 + reg;
                Al[r * LSTR + w * 32 + n]      = f2bf(fmaxf(acc[mt][0][reg] + b0c, 0.f));
                Al[r * LSTR + w * 32 + 16 + n] = f2bf(fmaxf(acc[mt][1][reg] + b1c, 0.f));
            }
        }
    }
    __syncthreads();

#pragma unroll
    for (int mt = 0; mt < 4; ++mt)
#pragma unroll
        for (int nt = 0; nt < 2; ++nt)
            acc[mt][nt] = (floatx4){0.f, 0.f, 0.f, 0.f};
    {
        const uint4* Wq = (const uint4*)Wf5;
#pragma unroll
        for (int kk = 0; kk < 4; ++kk) {
            uint4 u0 = Wq[((w * 2 + 0) * 4 + kk) * 64 + lane];
            uint4 u1 = Wq[((w * 2 + 1) * 4 + kk) * 64 + lane];
            int ko = kk * 32 + q * 8;
#pragma unroll
            for (int mt = 0; mt < 4; ++mt) {
                short8 a = *(const short8*)&Al[(mt * 16 + n) * LSTR + ko];
                acc[mt][0] = __builtin_amdgcn_mfma_f32_16x16x32_bf16(a, *(short8*)&u0, acc[mt][0], 0, 0, 0);
                acc[mt][1] = __builtin_amdgcn_mfma_f32_16x16x32_bf16(a, *(short8*)&u1, acc[mt][1], 0, 0, 0);
            }
        }
    }
    {
        float b0c = b5[w * 32 + n], b1c = b5[w * 32 + 16 + n];
        float w0c = ow[w * 32 + n], w1c = ow[w * 32 + 16 + n];
#pragma unroll
        for (int mt = 0; mt < 4; ++mt) {
#pragma unroll
            for (int reg = 0; reg < 4; ++reg) {
                float h0 = fmaxf(acc[mt][0][reg] + b0c, 0.f);
                float h1 = fmaxf(acc[mt][1][reg] + b1c, 0.f);
                float p = fmaf(h0, w0c, h1 * w1c);
                p += __shfl_xor(p, 1);
                p += __shfl_xor(p, 2);
                p += __shfl_xor(p, 4);
                p += __shfl_xor(p, 8);
                if (n == 0) redH[w][mt * 16 + q * 4 + reg] = p;
            }
        }
        __syncthreads();
        if (tid < 64) {
            int r = row0 + tid;
            if (r < NN) {
                float z = (redH[0][tid] + redH[1][tid]) + (redH[2][tid] + redH[3][tid]) + ob[0];
                out[r] = 1.f / (1.f + expf(-z));
            }
        }
    }
}
#undef LSTR

// ---------------- gather: ELL fast path, static grid-stride, bf16 out ----------
template<int RELU>
__global__ __launch_bounds__(256) void k_gather(const int* __restrict__ rowptr,
                                                const int* __restrict__ csr,
                                                const int* __restrict__ ell,
                                                const uint4* __restrict__ HSq,
                                                const float* __restrict__ dis,
                                                const float* __restrict__ bias,
                                                unsigned short* __restrict__ OUT,
                                                float* __restrict__ colsum,
                                                float* __restrict__ colsumsq) {
    const int tid = threadIdx.x;
    const int lane = tid & 63;
    const int wid = tid >> 6;
    const int c = lane & 15;
    const int jj = lane >> 4;
    const int gwave = blockIdx.x * 4 + wid;

    float4 bia0 = ((const float4*)bias)[2 * c];
    float4 bia1 = ((const float4*)bias)[2 * c + 1];
    float sum[8], sq[8];
#pragma unroll
    for (int t = 0; t < 8; ++t) { sum[t] = 0.f; sq[t] = 0.f; }

    for (int r = gwave; r < NN; r += 8192) {
        int beg = rowptr[r], end = rowptr[r + 1];
        int d = end - beg;
        float a[8];
#pragma unroll
        for (int t = 0; t < 8; ++t) a[t] = 0.f;

        if (jj == 0) {   // self loop
            uint4 u = HSq[(size_t)r * 16 + c];
            float2 p0 = bf2x2(u.x), p1 = bf2x2(u.y), p2 = bf2x2(u.z), p3 = bf2x2(u.w);
            a[0] += p0.x; a[1] += p0.y; a[2] += p1.x; a[3] += p1.y;
            a[4] += p2.x; a[5] += p2.y; a[6] += p3.x; a[7] += p3.y;
        }

        if (d <= 32) {
            const int4* e4 = (const int4*)(ell + r * 32);
            int4 ia = e4[jj];
            int4 ib = e4[jj + 4];
            uint4 v0 = HSq[(size_t)ia.x * 16 + c];
            uint4 v1 = HSq[(size_t)ia.y * 16 + c];
            uint4 v2 = HSq[(size_t)ia.z * 16 + c];
            uint4 v3 = HSq[(size_t)ia.w * 16 + c];
            uint4 v4 = HSq[(size_t)ib.x * 16 + c];
            uint4 v5 = HSq[(size_t)ib.y * 16 + c];
            uint4 v6 = HSq[(size_t)ib.z * 16 + c];
            uint4 v7 = HSq[(size_t)ib.w * 16 + c];
            uint4 vs[8] = {v0, v1, v2, v3, v4, v5, v6, v7};
#pragma unroll
            for (int t = 0; t < 8; ++t) {
                float2 p0 = bf2x2(vs[t].x), p1 = bf2x2(vs[t].y);
                float2 p2 = bf2x2(vs[t].z), p3 = bf2x2(vs[t].w);
                a[0] += p0.x; a[1] += p0.y; a[2] += p1.x; a[3] += p1.y;
                a[4] += p2.x; a[5] += p2.y; a[6] += p3.x; a[7] += p3.y;
            }
        } else {
            int e1 = end - 1;
            for (int j = beg; j < end; j += 16) {
                int i0 = j + jj, i1 = j + 4 + jj, i2 = j + 8 + jj, i3 = j + 12 + jj;
                int s0 = csr[min(i0, e1)];
                int s1 = csr[min(i1, e1)];
                int s2 = csr[min(i2, e1)];
                int s3 = csr[min(i3, e1)];
                uint4 v0 = HSq[(size_t)s0 * 16 + c];
                uint4 v1 = HSq[(size_t)s1 * 16 + c];
                uint4 v2 = HSq[(size_t)s2 * 16 + c];
                uint4 v3 = HSq[(size_t)s3 * 16 + c];
                if (i0 < end) {
                    float2 p0 = bf2x2(v0.x), p1 = bf2x2(v0.y), p2 = bf2x2(v0.z), p3 = bf2x2(v0.w);
                    a[0] += p0.x; a[1] += p0.y; a[2] += p1.x; a[3] += p1.y;
                    a[4] += p2.x; a[5] += p2.y; a[6] += p3.x; a[7] += p3.y;
                }
                if (i1 < end) {
                    float2 p0 = bf2x2(v1.x), p1 = bf2x2(v1.y), p2 = bf2x2(v1.z), p3 = bf2x2(v1.w);
                    a[0] += p0.x; a[1] += p0.y; a[2] += p1.x; a[3] += p1.y;
                    a[4] += p2.x; a[5] += p2.y; a[6] += p3.x; a[7] += p3.y;
                }
                if (i2 < end) {
                    float2 p0 = bf2x2(v2.x), p1 = bf2x2(v2.y), p2 = bf2x2(v2.z), p3 = bf2x2(v2.w);
                    a[0] += p0.x; a[1] += p0.y; a[2] += p1.x; a[3] += p1.y;
                    a[4] += p2.x; a[5] += p2.y; a[6] += p3.x; a[7] += p3.y;
                }
                if (i3 < end) {
                    float2 p0 = bf2x2(v3.x), p1 = bf2x2(v3.y), p2 = bf2x2(v3.z), p3 = bf2x2(v3.w);
                    a[0] += p0.x; a[1] += p0.y; a[2] += p1.x; a[3] += p1.y;
                    a[4] += p2.x; a[5] += p2.y; a[6] += p3.x; a[7] += p3.y;
                }
            }
        }

#pragma unroll
        for (int t = 0; t < 8; ++t) {
            a[t] += __shfl_xor(a[t], 16);
            a[t] += __shfl_xor(a[t], 32);
        }

        if (jj == 0) {
            float dr = dis[r];
            float v[8];
            v[0] = fmaf(dr, a[0], bia0.x); v[1] = fmaf(dr, a[1], bia0.y);
            v[2] = fmaf(dr, a[2], bia0.z); v[3] = fmaf(dr, a[3], bia0.w);
            v[4] = fmaf(dr, a[4], bia1.x); v[5] = fmaf(dr, a[5], bia1.y);
            v[6] = fmaf(dr, a[6], bia1.z); v[7] = fmaf(dr, a[7], bia1.w);
            if (RELU) {
#pragma unroll
                for (int t = 0; t < 8; ++t) v[t] = fmaxf(v[t], 0.f);
            }
            unsigned int p[4];
#pragma unroll
            for (int t = 0; t < 4; ++t)
                p[t] = (unsigned int)f2bf(v[2 * t]) | ((unsigned int)f2bf(v[2 * t + 1]) << 16);
            *(uint4*)&OUT[(size_t)r * DD + c * 8] = make_uint4(p[0], p[1], p[2], p[3]);
#pragma unroll
            for (int t = 0; t < 8; ++t) { sum[t] += v[t]; sq[t] += v[t] * v[t]; }
        }
    }

    __shared__ float redS[4][16][8];
    __shared__ float redQ[4][16][8];
    if (jj == 0) {
#pragma unroll
        for (int t = 0; t < 8; ++t) { redS[wid][c][t] = sum[t]; redQ[wid][c][t] = sq[t]; }
    }
    __syncthreads();
    if (tid < 128) {
        int ci = tid >> 3, ct = tid & 7;
        float S = (redS[0][ci][ct] + redS[1][ci][ct]) + (redS[2][ci][ct] + redS[3][ci][ct]);
        float Q = (redQ[0][ci][ct] + redQ[1][ci][ct]) + (redQ[2][ci][ct] + redQ[3][ci][ct]);
        atomicAdd(&colsum[tid], S);
        atomicAdd(&colsumsq[tid], Q);
    }
}

extern "C" void kernel_launch(void* const* d_in, const int* in_sizes, int n_in,
                              void* d_out, int out_size, void* d_ws, size_t ws_size,
                              hipStream_t stream) {
    const float* x      = (const float*)d_in[0];
    const int*   ei     = (const int*)d_in[1];
    const float* conv_w = (const float*)d_in[2];
    const float* conv_b = (const float*)d_in[3];
    const float* bn_g   = (const float*)d_in[4];
    const float* bn_b   = (const float*)d_in[5];
    const float* mlp_w  = (const float*)d_in[6];
    const float* mlp_b  = (const float*)d_in[7];
    const float* out_w  = (const float*)d_in[8];
    const float* out_b  = (const float*)d_in[9];
    float* out = (float*)d_out;

    const size_t ND4 = (size_t)NN * DD * 4;   // 25,600,000 B
    char* ws = (char*)d_ws;
    size_t off = 0;
    unsigned short* B0 = (unsigned short*)(ws + off); off += ND4 / 2;        // bf16 features
    unsigned short* B1b = (unsigned short*)(ws + off); off += ND4 / 2 + 256; // bf16 HS + pad row
    int*   deg     = (int*)  (ws + off); off += 204800;             // zeroed region start
    float* cs3     = (float*)(ws + off); off += 3 * 512;
    float* css3    = (float*)(ws + off); off += 3 * 512;            // zeroed region end
    float* dis     = (float*)(ws + off); off += 204800;
    int*   rowptr  = (int*)  (ws + off); off += 204804 + 60;
    int*   cursor  = (int*)  (ws + off); off += 204800;
    int*   bsum    = (int*)  (ws + off); off += 1024;
    unsigned short* Wfb = (unsigned short*)(ws + off); off += 5 * 16384 * 2;
    int*   csr     = (int*)  (ws + off); off += (size_t)EE * 4;
    int*   ell     = (int*)  (ws + off); off += (size_t)NN * 32 * 4;  // 6.4MB
    // total ≈ 36.5 MB

    const int gemm_grid = (NN + 63) / 64;     // 782
    const int nscan = (NN + 255) / 256;       // 196
    const int gather_grid = 2048;             // 8192 waves

    hipMemsetAsync(deg, 0, 204800 + 6 * 512, stream);

    k_deg<<<(EE + 255) / 256, 256, 0, stream>>>(ei, deg);
    k_scan_block<<<nscan, 256, 0, stream>>>(deg, cursor, bsum);
    k_scan_final<<<nscan, 256, 0, stream>>>(deg, cursor, bsum, nscan, rowptr, cursor, dis, ell);
    k_fill<<<(EE + 255) / 256, 256, 0, stream>>>(ei, rowptr, cursor, csr, ell);
    k_wprep<<<321, 256, 0, stream>>>(conv_w, mlp_w, Wfb, (unsigned int*)(B1b + (size_t)NN * DD));

    // ---- layer 0 ----
    k_gemm_conv<0><<<gemm_grid, 256, 0, stream>>>(x, Wfb, dis,
        nullptr, nullptr, nullptr, nullptr, B1b);
    k_gather<0><<<gather_grid, 256, 0, stream>>>(rowptr, csr, ell, (const uint4*)B1b, dis, conv_b, B0, cs3, css3);

    // ---- layer 1 ----
    k_gemm_conv<1><<<gemm_grid, 256, 0, stream>>>(B0, Wfb + 16384, dis,
        cs3, css3, bn_g, bn_b, B1b);
    k_gather<0><<<gather_grid, 256, 0, stream>>>(rowptr, csr, ell, (const uint4*)B1b, dis, conv_b + DD, B0, cs3 + 128, css3 + 128);

    // ---- layer 2 ----
    k_gemm_conv<1><<<gemm_grid, 256, 0, stream>>>(B0, Wfb + 2 * 16384, dis,
        cs3 + 128, css3 + 128, bn_g + DD, bn_b + DD, B1b);
    k_gather<1><<<gather_grid, 256, 0, stream>>>(rowptr, csr, ell, (const uint4*)B1b, dis, conv_b + 2 * DD, B0, cs3 + 256, css3 + 256);

    // ---- fused MLP + head ----
    k_mlp_head<<<gemm_grid, 256, 0, stream>>>((const unsigned int*)B0, Wfb + 3 * 16384, Wfb + 4 * 16384,
        mlp_b, mlp_b + DD, cs3 + 256, css3 + 256, bn_g + DD, bn_b + DD, out_w, out_b, out);
}

// Round 17
// 438.686 us; speedup vs baseline: 1.2185x; 1.0256x over previous
//
#include <hip/hip_runtime.h>
#include <hip/hip_bf16.h>

#define NN 50000
#define EE 800000
#define DD 128

typedef __attribute__((ext_vector_type(8))) short short8;
typedef __attribute__((ext_vector_type(4))) float floatx4;

__device__ __forceinline__ unsigned short f2bf(float f) {   // RNE
    unsigned int x = __float_as_uint(f);
    unsigned int r = x + 0x7fffu + ((x >> 16) & 1u);
    return (unsigned short)(r >> 16);
}
__device__ __forceinline__ float2 bf2x2(unsigned int u) {   // [lo,hi] bf16 pair
    return make_float2(__uint_as_float(u << 16), __uint_as_float(u & 0xffff0000u));
}

// ---------------- W prep (fragment order) + zero pad-row/deg/stats ----------------
// Runs FIRST; replaces the memset dispatch.
__global__ void k_wprep(const float* __restrict__ conv_w, const float* __restrict__ mlp_w,
                        unsigned short* __restrict__ Wf, unsigned int* __restrict__ hsrow,
                        int* __restrict__ deg, float* __restrict__ stats) {
    int g = blockIdx.x * 256 + threadIdx.x;
    if (g < 81920) {
        int m = g >> 14;
        int idx = g & 16383;
        int j  = idx & 7;
        int n  = (idx >> 3) & 15;
        int q  = (idx >> 7) & 3;
        int kk = (idx >> 9) & 3;
        int nt = (idx >> 11) & 1;
        int w  = (idx >> 12) & 3;
        int k = kk * 32 + q * 8 + j;
        int c = w * 32 + nt * 16 + n;
        const float* src = (m < 3) ? (conv_w + m * 16384) : (mlp_w + (m - 3) * 16384);
        Wf[g] = f2bf(src[k * 128 + c]);
    } else if (g < 81984) {
        hsrow[g - 81920] = 0u;                  // zero pad row HS[NN]
    } else if (g < 133184) {
        deg[g - 81984] = 0;                     // zero degree array (NN, padded to 51200)
    } else if (g < 133568) {
        stats[g - 133184] = 0.f;                // zero cs3/css3 (384 floats)
    }
}

// ---------------- degree (guarded) ----------------
__global__ void k_deg(const int* __restrict__ ei, int* __restrict__ deg) {
    int e = blockIdx.x * 256 + threadIdx.x;
    if (e < EE) {
        int d = ei[EE + e];
        if (d >= 0 && d < NN) atomicAdd(&deg[d], 1);
    }
}

// ---------------- CSR scan stage 1 ----------------
__global__ void k_scan_block(const int* __restrict__ deg, int* __restrict__ scanned,
                             int* __restrict__ blocksum) {
    __shared__ int lds[256];
    int t = threadIdx.x;
    int i = blockIdx.x * 256 + t;
    int v = (i < NN) ? deg[i] : 0;
    lds[t] = v;
    __syncthreads();
    for (int off = 1; off < 256; off <<= 1) {
        int add = (t >= off) ? lds[t - off] : 0;
        __syncthreads();
        lds[t] += add;
        __syncthreads();
    }
    if (i < NN) scanned[i] = lds[t];
    if (t == 255) blocksum[blockIdx.x] = lds[255];
}

// ---------------- CSR scan stage 2 (top-scan + final + dis + full-row ELL pads) ----
__global__ void k_scan_final(const int* __restrict__ deg, const int* __restrict__ scanned,
                             const int* __restrict__ blocksum, int nb,
                             int* __restrict__ rowptr, int* __restrict__ cursor,
                             float* __restrict__ dis, int* __restrict__ ell) {
    __shared__ int lds[256];
    int t = threadIdx.x;
    int v = (t < nb) ? blocksum[t] : 0;
    lds[t] = v;
    __syncthreads();
    for (int off = 1; off < 256; off <<= 1) {
        int add = (t >= off) ? lds[t - off] : 0;
        __syncthreads();
        lds[t] += add;
        __syncthreads();
    }
    int boff = (blockIdx.x == 0) ? 0 : lds[blockIdx.x - 1];
    if (blockIdx.x == 0 && t == 0) rowptr[NN] = lds[nb - 1];
    int i = blockIdx.x * 256 + t;
    if (i < NN) {
        int d = deg[i];
        int rv = scanned[i] - d + boff;
        rowptr[i] = rv;
        cursor[i] = rv;
        dis[i] = rsqrtf((float)d + 1.0f);
        int4 pad = make_int4(NN, NN, NN, NN);   // whole row = pad; k_fill overwrites real
        int4* ep = (int4*)(ell + i * 32);
#pragma unroll
        for (int s = 0; s < 8; ++s) ep[s] = pad;
    }
}

// csr + ELL real slots in one pass
__global__ void k_fill(const int* __restrict__ ei, const int* __restrict__ rowptr,
                       int* __restrict__ cursor, int* __restrict__ csr,
                       int* __restrict__ ell) {
    int e = blockIdx.x * 256 + threadIdx.x;
    if (e < EE) {
        int s = ei[e];
        int d = ei[EE + e];
        if ((unsigned)s < (unsigned)NN && (unsigned)d < (unsigned)NN) {
            int pos = atomicAdd(&cursor[d], 1);
            csr[pos] = s;
            int slot = pos - rowptr[d];
            if (slot < 32) ell[d * 32 + slot] = s;
        }
    }
}

// ---------------- conv MFMA GEMM: HS = pro(IN) @ W * dis -> bf16 ----------------
// 32-row x 128-col blocks, 4 waves (wave = 32-col slice). 1563 blocks = 6.1/CU.
// PRO 0: IN fp32, no BN (layer 0).  PRO 1: IN bf16, BN+relu while staging.
#define LSTR 136
template<int PRO>
__global__ __launch_bounds__(256) void k_gemm_conv(const void* __restrict__ INv,
                                                   const unsigned short* __restrict__ Wf,
                                                   const float* __restrict__ dis,
                                                   const float* __restrict__ cs,
                                                   const float* __restrict__ css,
                                                   const float* __restrict__ gamma,
                                                   const float* __restrict__ beta,
                                                   unsigned short* __restrict__ OUT) {
    __shared__ unsigned short Al[32 * LSTR];    // 8.7KB
    __shared__ float bnscL[128], bnshL[128];
    const int tid = threadIdx.x;
    const int lane = tid & 63;
    const int w = tid >> 6;
    const int row0 = blockIdx.x * 32;

    if (PRO) {
        if (tid < 128) {
            const float invn = 1.f / (float)NN;
            float mean = cs[tid] * invn;
            float var = css[tid] * invn - mean * mean;
            float sc = gamma[tid] * rsqrtf(fmaxf(var, 0.f) + 1e-5f);
            bnscL[tid] = sc;
            bnshL[tid] = beta[tid] - mean * sc;
        }
        __syncthreads();
    }

    short8 bf[2][4];
    {
        const uint4* Wq = (const uint4*)Wf;
#pragma unroll
        for (int nt = 0; nt < 2; ++nt)
#pragma unroll
            for (int kk = 0; kk < 4; ++kk) {
                uint4 u = Wq[((w * 2 + nt) * 4 + kk) * 64 + lane];
                bf[nt][kk] = *(short8*)&u;
            }
    }

    // stage A: thread -> row tid>>3 (0..31), k-octant (tid&7)*16
    {
        int r = tid >> 3, ko8 = (tid & 7) * 16;
        int gr = row0 + r;
        unsigned short tmp[16];
        if (PRO == 0) {
            const float* IN = (const float*)INv;
#pragma unroll
            for (int i = 0; i < 4; ++i) {
                float4 v = make_float4(0.f, 0.f, 0.f, 0.f);
                if (gr < NN) v = *(const float4*)&IN[(size_t)gr * DD + ko8 + i * 4];
                tmp[i * 4 + 0] = f2bf(v.x); tmp[i * 4 + 1] = f2bf(v.y);
                tmp[i * 4 + 2] = f2bf(v.z); tmp[i * 4 + 3] = f2bf(v.w);
            }
        } else {
            const unsigned int* inu = (const unsigned int*)INv;
#pragma unroll
            for (int i = 0; i < 2; ++i) {
                uint4 u = make_uint4(0u, 0u, 0u, 0u);
                if (gr < NN) u = *(const uint4*)&inu[(size_t)gr * 64 + (ko8 >> 1) + i * 4];
                float2 p0 = bf2x2(u.x), p1 = bf2x2(u.y), p2 = bf2x2(u.z), p3 = bf2x2(u.w);
                float vv[8] = {p0.x, p0.y, p1.x, p1.y, p2.x, p2.y, p3.x, p3.y};
#pragma unroll
                for (int j = 0; j < 8; ++j) {
                    float t2 = fmaf(vv[j], bnscL[ko8 + i * 8 + j], bnshL[ko8 + i * 8 + j]);
                    tmp[i * 8 + j] = f2bf(fmaxf(t2, 0.f));
                }
            }
        }
#pragma unroll
        for (int j = 0; j < 2; ++j)
            *(uint4*)&Al[r * LSTR + ko8 + j * 8] = ((uint4*)tmp)[j];
    }
    __syncthreads();

    const int n = lane & 15, q = lane >> 4;
    floatx4 acc[2][2];
#pragma unroll
    for (int mt = 0; mt < 2; ++mt)
#pragma unroll
        for (int nt = 0; nt < 2; ++nt)
            acc[mt][nt] = (floatx4){0.f, 0.f, 0.f, 0.f};

#pragma unroll
    for (int kk = 0; kk < 4; ++kk) {
        int ko = kk * 32 + q * 8;
#pragma unroll
        for (int mt = 0; mt < 2; ++mt) {
            short8 a = *(const short8*)&Al[(mt * 16 + n) * LSTR + ko];
            acc[mt][0] = __builtin_amdgcn_mfma_f32_16x16x32_bf16(a, bf[0][kk], acc[mt][0], 0, 0, 0);
            acc[mt][1] = __builtin_amdgcn_mfma_f32_16x16x32_bf16(a, bf[1][kk], acc[mt][1], 0, 0, 0);
        }
    }

#pragma unroll
    for (int mt = 0; mt < 2; ++mt) {
#pragma unroll
        for (int reg = 0; reg < 4; ++reg) {
            int r = row0 + mt * 16 + q * 4 + reg;
            if (r < NN) {
                float sc = dis[r];
                OUT[(size_t)r * DD + w * 32 + n]      = f2bf(acc[mt][0][reg] * sc);
                OUT[(size_t)r * DD + w * 32 + 16 + n] = f2bf(acc[mt][1][reg] * sc);
            }
        }
    }
}

// ---------------- fused MLP + head (bf16 input, BN no relu), 32-row blocks ------
__global__ __launch_bounds__(256) void k_mlp_head(const unsigned int* __restrict__ INu,
                                                  const unsigned short* __restrict__ Wf4,
                                                  const unsigned short* __restrict__ Wf5,
                                                  const float* __restrict__ b4,
                                                  const float* __restrict__ b5,
                                                  const float* __restrict__ cs,
                                                  const float* __restrict__ css,
                                                  const float* __restrict__ gamma,
                                                  const float* __restrict__ beta,
                                                  const float* __restrict__ ow,
                                                  const float* __restrict__ ob,
                                                  float* __restrict__ out) {
    __shared__ unsigned short Al[32 * LSTR];
    __shared__ float bnscL[128], bnshL[128];
    __shared__ float redH[4][32];
    const int tid = threadIdx.x;
    const int lane = tid & 63;
    const int w = tid >> 6;
    const int row0 = blockIdx.x * 32;
    const int n = lane & 15, q = lane >> 4;

    if (tid < 128) {
        const float invn = 1.f / (float)NN;
        float mean = cs[tid] * invn;
        float var = css[tid] * invn - mean * mean;
        float sc = gamma[tid] * rsqrtf(fmaxf(var, 0.f) + 1e-5f);
        bnscL[tid] = sc;
        bnshL[tid] = beta[tid] - mean * sc;
    }
    __syncthreads();

    {
        int r = tid >> 3, ko8 = (tid & 7) * 16;
        int gr = row0 + r;
        unsigned short tmp[16];
#pragma unroll
        for (int i = 0; i < 2; ++i) {
            uint4 u = make_uint4(0u, 0u, 0u, 0u);
            if (gr < NN) u = *(const uint4*)&INu[(size_t)gr * 64 + (ko8 >> 1) + i * 4];
            float2 p0 = bf2x2(u.x), p1 = bf2x2(u.y), p2 = bf2x2(u.z), p3 = bf2x2(u.w);
            float vv[8] = {p0.x, p0.y, p1.x, p1.y, p2.x, p2.y, p3.x, p3.y};
#pragma unroll
            for (int j = 0; j < 8; ++j) {
                float t2 = fmaf(vv[j], bnscL[ko8 + i * 8 + j], bnshL[ko8 + i * 8 + j]);
                tmp[i * 8 + j] = f2bf(t2);
            }
        }
#pragma unroll
        for (int j = 0; j < 2; ++j)
            *(uint4*)&Al[r * LSTR + ko8 + j * 8] = ((uint4*)tmp)[j];
    }
    __syncthreads();

    floatx4 acc[2][2];
#pragma unroll
    for (int mt = 0; mt < 2; ++mt)
#pragma unroll
        for (int nt = 0; nt < 2; ++nt)
            acc[mt][nt] = (floatx4){0.f, 0.f, 0.f, 0.f};
    {
        const uint4* Wq = (const uint4*)Wf4;
#pragma unroll
        for (int kk = 0; kk < 4; ++kk) {
            uint4 u0 = Wq[((w * 2 + 0) * 4 + kk) * 64 + lane];
            uint4 u1 = Wq[((w * 2 + 1) * 4 + kk) * 64 + lane];
            int ko = kk * 32 + q * 8;
#pragma unroll
            for (int mt = 0; mt < 2; ++mt) {
                short8 a = *(const short8*)&Al[(mt * 16 + n) * LSTR + ko];
                acc[mt][0] = __builtin_amdgcn_mfma_f32_16x16x32_bf16(a, *(short8*)&u0, acc[mt][0], 0, 0, 0);
                acc[mt][1] = __builtin_amdgcn_mfma_f32_16x16x32_bf16(a, *(short8*)&u1, acc[mt][1], 0, 0, 0);
            }
        }
    }
    __syncthreads();

    {
        float b0c = b4[w * 32 + n], b1c = b4[w * 32 + 16 + n];
#pragma unroll
        for (int mt = 0; mt < 2; ++mt) {
#pragma unroll
            for (int reg = 0; reg < 4; ++reg) {
                int r = mt * 16 + q * 4 + reg;
                Al[r * LSTR + w * 32 + n]      = f2bf(fmaxf(acc[mt][0][reg] + b0c, 0.f));
                Al[r * LSTR + w * 32 + 16 + n] = f2bf(fmaxf(acc[mt][1][reg] + b1c, 0.f));
            }
        }
    }
    __syncthreads();

#pragma unroll
    for (int mt = 0; mt < 2; ++mt)
#pragma unroll
        for (int nt = 0; nt < 2; ++nt)
            acc[mt][nt] = (floatx4){0.f, 0.f, 0.f, 0.f};
    {
        const uint4* Wq = (const uint4*)Wf5;
#pragma unroll
        for (int kk = 0; kk < 4; ++kk) {
            uint4 u0 = Wq[((w * 2 + 0) * 4 + kk) * 64 + lane];
            uint4 u1 = Wq[((w * 2 + 1) * 4 + kk) * 64 + lane];
            int ko = kk * 32 + q * 8;
#pragma unroll
            for (int mt = 0; mt < 2; ++mt) {
                short8 a = *(const short8*)&Al[(mt * 16 + n) * LSTR + ko];
                acc[mt][0] = __builtin_amdgcn_mfma_f32_16x16x32_bf16(a, *(short8*)&u0, acc[mt][0], 0, 0, 0);
                acc[mt][1] = __builtin_amdgcn_mfma_f32_16x16x32_bf16(a, *(short8*)&u1, acc[mt][1], 0, 0, 0);
            }
        }
    }
    {
        float b0c = b5[w * 32 + n], b1c = b5[w * 32 + 16 + n];
        float w0c = ow[w * 32 + n], w1c = ow[w * 32 + 16 + n];
#pragma unroll
        for (int mt = 0; mt < 2; ++mt) {
#pragma unroll
            for (int reg = 0; reg < 4; ++reg) {
                float h0 = fmaxf(acc[mt][0][reg] + b0c, 0.f);
                float h1 = fmaxf(acc[mt][1][reg] + b1c, 0.f);
                float p = fmaf(h0, w0c, h1 * w1c);
                p += __shfl_xor(p, 1);
                p += __shfl_xor(p, 2);
                p += __shfl_xor(p, 4);
                p += __shfl_xor(p, 8);
                if (n == 0) redH[w][mt * 16 + q * 4 + reg] = p;
            }
        }
        __syncthreads();
        if (tid < 32) {
            int r = row0 + tid;
            if (r < NN) {
                float z = (redH[0][tid] + redH[1][tid]) + (redH[2][tid] + redH[3][tid]) + ob[0];
                out[r] = 1.f / (1.f + expf(-z));
            }
        }
    }
}
#undef LSTR

// ---------------- gather: ELL fast path, static grid-stride, bf16 out ----------
template<int RELU>
__global__ __launch_bounds__(256) void k_gather(const int* __restrict__ rowptr,
                                                const int* __restrict__ csr,
                                                const int* __restrict__ ell,
                                                const uint4* __restrict__ HSq,
                                                const float* __restrict__ dis,
                                                const float* __restrict__ bias,
                                                unsigned short* __restrict__ OUT,
                                                float* __restrict__ colsum,
                                                float* __restrict__ colsumsq) {
    const int tid = threadIdx.x;
    const int lane = tid & 63;
    const int wid = tid >> 6;
    const int c = lane & 15;
    const int jj = lane >> 4;
    const int gwave = blockIdx.x * 4 + wid;

    float4 bia0 = ((const float4*)bias)[2 * c];
    float4 bia1 = ((const float4*)bias)[2 * c + 1];
    float sum[8], sq[8];
#pragma unroll
    for (int t = 0; t < 8; ++t) { sum[t] = 0.f; sq[t] = 0.f; }

    for (int r = gwave; r < NN; r += 8192) {
        int beg = rowptr[r], end = rowptr[r + 1];
        int d = end - beg;
        float a[8];
#pragma unroll
        for (int t = 0; t < 8; ++t) a[t] = 0.f;

        if (jj == 0) {   // self loop
            uint4 u = HSq[(size_t)r * 16 + c];
            float2 p0 = bf2x2(u.x), p1 = bf2x2(u.y), p2 = bf2x2(u.z), p3 = bf2x2(u.w);
            a[0] += p0.x; a[1] += p0.y; a[2] += p1.x; a[3] += p1.y;
            a[4] += p2.x; a[5] += p2.y; a[6] += p3.x; a[7] += p3.y;
        }

        if (d <= 32) {
            const int4* e4 = (const int4*)(ell + r * 32);
            int4 ia = e4[jj];
            int4 ib = e4[jj + 4];
            uint4 v0 = HSq[(size_t)ia.x * 16 + c];
            uint4 v1 = HSq[(size_t)ia.y * 16 + c];
            uint4 v2 = HSq[(size_t)ia.z * 16 + c];
            uint4 v3 = HSq[(size_t)ia.w * 16 + c];
            uint4 v4 = HSq[(size_t)ib.x * 16 + c];
            uint4 v5 = HSq[(size_t)ib.y * 16 + c];
            uint4 v6 = HSq[(size_t)ib.z * 16 + c];
            uint4 v7 = HSq[(size_t)ib.w * 16 + c];
            uint4 vs[8] = {v0, v1, v2, v3, v4, v5, v6, v7};
#pragma unroll
            for (int t = 0; t < 8; ++t) {
                float2 p0 = bf2x2(vs[t].x), p1 = bf2x2(vs[t].y);
                float2 p2 = bf2x2(vs[t].z), p3 = bf2x2(vs[t].w);
                a[0] += p0.x; a[1] += p0.y; a[2] += p1.x; a[3] += p1.y;
                a[4] += p2.x; a[5] += p2.y; a[6] += p3.x; a[7] += p3.y;
            }
        } else {
            int e1 = end - 1;
            for (int j = beg; j < end; j += 16) {
                int i0 = j + jj, i1 = j + 4 + jj, i2 = j + 8 + jj, i3 = j + 12 + jj;
                int s0 = csr[min(i0, e1)];
                int s1 = csr[min(i1, e1)];
                int s2 = csr[min(i2, e1)];
                int s3 = csr[min(i3, e1)];
                uint4 v0 = HSq[(size_t)s0 * 16 + c];
                uint4 v1 = HSq[(size_t)s1 * 16 + c];
                uint4 v2 = HSq[(size_t)s2 * 16 + c];
                uint4 v3 = HSq[(size_t)s3 * 16 + c];
                if (i0 < end) {
                    float2 p0 = bf2x2(v0.x), p1 = bf2x2(v0.y), p2 = bf2x2(v0.z), p3 = bf2x2(v0.w);
                    a[0] += p0.x; a[1] += p0.y; a[2] += p1.x; a[3] += p1.y;
                    a[4] += p2.x; a[5] += p2.y; a[6] += p3.x; a[7] += p3.y;
                }
                if (i1 < end) {
                    float2 p0 = bf2x2(v1.x), p1 = bf2x2(v1.y), p2 = bf2x2(v1.z), p3 = bf2x2(v1.w);
                    a[0] += p0.x; a[1] += p0.y; a[2] += p1.x; a[3] += p1.y;
                    a[4] += p2.x; a[5] += p2.y; a[6] += p3.x; a[7] += p3.y;
                }
                if (i2 < end) {
                    float2 p0 = bf2x2(v2.x), p1 = bf2x2(v2.y), p2 = bf2x2(v2.z), p3 = bf2x2(v2.w);
                    a[0] += p0.x; a[1] += p0.y; a[2] += p1.x; a[3] += p1.y;
                    a[4] += p2.x; a[5] += p2.y; a[6] += p3.x; a[7] += p3.y;
                }
                if (i3 < end) {
                    float2 p0 = bf2x2(v3.x), p1 = bf2x2(v3.y), p2 = bf2x2(v3.z), p3 = bf2x2(v3.w);
                    a[0] += p0.x; a[1] += p0.y; a[2] += p1.x; a[3] += p1.y;
                    a[4] += p2.x; a[5] += p2.y; a[6] += p3.x; a[7] += p3.y;
                }
            }
        }

#pragma unroll
        for (int t = 0; t < 8; ++t) {
            a[t] += __shfl_xor(a[t], 16);
            a[t] += __shfl_xor(a[t], 32);
        }

        if (jj == 0) {
            float dr = dis[r];
            float v[8];
            v[0] = fmaf(dr, a[0], bia0.x); v[1] = fmaf(dr, a[1], bia0.y);
            v[2] = fmaf(dr, a[2], bia0.z); v[3] = fmaf(dr, a[3], bia0.w);
            v[4] = fmaf(dr, a[4], bia1.x); v[5] = fmaf(dr, a[5], bia1.y);
            v[6] = fmaf(dr, a[6], bia1.z); v[7] = fmaf(dr, a[7], bia1.w);
            if (RELU) {
#pragma unroll
                for (int t = 0; t < 8; ++t) v[t] = fmaxf(v[t], 0.f);
            }
            unsigned int p[4];
#pragma unroll
            for (int t = 0; t < 4; ++t)
                p[t] = (unsigned int)f2bf(v[2 * t]) | ((unsigned int)f2bf(v[2 * t + 1]) << 16);
            *(uint4*)&OUT[(size_t)r * DD + c * 8] = make_uint4(p[0], p[1], p[2], p[3]);
#pragma unroll
            for (int t = 0; t < 8; ++t) { sum[t] += v[t]; sq[t] += v[t] * v[t]; }
        }
    }

    __shared__ float redS[4][16][8];
    __shared__ float redQ[4][16][8];
    if (jj == 0) {
#pragma unroll
        for (int t = 0; t < 8; ++t) { redS[wid][c][t] = sum[t]; redQ[wid][c][t] = sq[t]; }
    }
    __syncthreads();
    if (tid < 128) {
        int ci = tid >> 3, ct = tid & 7;
        float S = (redS[0][ci][ct] + redS[1][ci][ct]) + (redS[2][ci][ct] + redS[3][ci][ct]);
        float Q = (redQ[0][ci][ct] + redQ[1][ci][ct]) + (redQ[2][ci][ct] + redQ[3][ci][ct]);
        atomicAdd(&colsum[tid], S);
        atomicAdd(&colsumsq[tid], Q);
    }
}

extern "C" void kernel_launch(void* const* d_in, const int* in_sizes, int n_in,
                              void* d_out, int out_size, void* d_ws, size_t ws_size,
                              hipStream_t stream) {
    const float* x      = (const float*)d_in[0];
    const int*   ei     = (const int*)d_in[1];
    const float* conv_w = (const float*)d_in[2];
    const float* conv_b = (const float*)d_in[3];
    const float* bn_g   = (const float*)d_in[4];
    const float* bn_b   = (const float*)d_in[5];
    const float* mlp_w  = (const float*)d_in[6];
    const float* mlp_b  = (const float*)d_in[7];
    const float* out_w  = (const float*)d_in[8];
    const float* out_b  = (const float*)d_in[9];
    float* out = (float*)d_out;

    const size_t ND4 = (size_t)NN * DD * 4;   // 25,600,000 B
    char* ws = (char*)d_ws;
    size_t off = 0;
    unsigned short* B0 = (unsigned short*)(ws + off); off += ND4 / 2;        // bf16 features
    unsigned short* B1b = (unsigned short*)(ws + off); off += ND4 / 2 + 256; // bf16 HS + pad row
    int*   deg     = (int*)  (ws + off); off += 204800;
    float* cs3     = (float*)(ws + off); off += 3 * 512;
    float* css3    = (float*)(ws + off); off += 3 * 512;
    float* dis     = (float*)(ws + off); off += 204800;
    int*   rowptr  = (int*)  (ws + off); off += 204804 + 60;
    int*   cursor  = (int*)  (ws + off); off += 204800;
    int*   bsum    = (int*)  (ws + off); off += 1024;
    unsigned short* Wfb = (unsigned short*)(ws + off); off += 5 * 16384 * 2;
    int*   csr     = (int*)  (ws + off); off += (size_t)EE * 4;
    int*   ell     = (int*)  (ws + off); off += (size_t)NN * 32 * 4;  // 6.4MB
    // total ≈ 36.5 MB

    const int gemm_grid = (NN + 31) / 32;     // 1563 blocks, ~6.1/CU
    const int nscan = (NN + 255) / 256;       // 196
    const int gather_grid = 2048;             // 8192 waves

    // wprep first: converts weights AND zeroes deg/stats (replaces memset)
    k_wprep<<<522, 256, 0, stream>>>(conv_w, mlp_w, Wfb,
        (unsigned int*)(B1b + (size_t)NN * DD), deg, cs3);

    k_deg<<<(EE + 255) / 256, 256, 0, stream>>>(ei, deg);
    k_scan_block<<<nscan, 256, 0, stream>>>(deg, cursor, bsum);
    k_scan_final<<<nscan, 256, 0, stream>>>(deg, cursor, bsum, nscan, rowptr, cursor, dis, ell);
    k_fill<<<(EE + 255) / 256, 256, 0, stream>>>(ei, rowptr, cursor, csr, ell);

    // ---- layer 0 ----
    k_gemm_conv<0><<<gemm_grid, 256, 0, stream>>>(x, Wfb, dis,
        nullptr, nullptr, nullptr, nullptr, B1b);
    k_gather<0><<<gather_grid, 256, 0, stream>>>(rowptr, csr, ell, (const uint4*)B1b, dis, conv_b, B0, cs3, css3);

    // ---- layer 1 ----
    k_gemm_conv<1><<<gemm_grid, 256, 0, stream>>>(B0, Wfb + 16384, dis,
        cs3, css3, bn_g, bn_b, B1b);
    k_gather<0><<<gather_grid, 256, 0, stream>>>(rowptr, csr, ell, (const uint4*)B1b, dis, conv_b + DD, B0, cs3 + 128, css3 + 128);

    // ---- layer 2 ----
    k_gemm_conv<1><<<gemm_grid, 256, 0, stream>>>(B0, Wfb + 2 * 16384, dis,
        cs3 + 128, css3 + 128, bn_g + DD, bn_b + DD, B1b);
    k_gather<1><<<gather_grid, 256, 0, stream>>>(rowptr, csr, ell, (const uint4*)B1b, dis, conv_b + 2 * DD, B0, cs3 + 256, css3 + 256);

    // ---- fused MLP + head ----
    k_mlp_head<<<gemm_grid, 256, 0, stream>>>((const unsigned int*)B0, Wfb + 3 * 16384, Wfb + 4 * 16384,
        mlp_b, mlp_b + DD, cs3 + 256, css3 + 256, bn_g + DD, bn_b + DD, out_w, out_b, out);
}

// Round 18
// 383.280 us; speedup vs baseline: 1.3946x; 1.1446x over previous
//
#include <hip/hip_runtime.h>
#include <hip/hip_bf16.h>

#define NN 50000
#define EE 800000
#define DD 128
#define OVCAP 8192

typedef __attribute__((ext_vector_type(8))) short short8;
typedef __attribute__((ext_vector_type(4))) float floatx4;

__device__ __forceinline__ unsigned short f2bf(float f) {   // RNE
    unsigned int x = __float_as_uint(f);
    unsigned int r = x + 0x7fffu + ((x >> 16) & 1u);
    return (unsigned short)(r >> 16);
}
__device__ __forceinline__ float2 bf2x2(unsigned int u) {   // [lo,hi] bf16 pair
    return make_float2(__uint_as_float(u << 16), __uint_as_float(u & 0xffff0000u));
}

// ---------------- W prep (fragment order) + ELL all-pad init + all zeroing ------
// Runs FIRST; replaces memset + separate ELL init.
__global__ void k_wprep(const float* __restrict__ conv_w, const float* __restrict__ mlp_w,
                        unsigned short* __restrict__ Wf, unsigned int* __restrict__ hsrow,
                        int* __restrict__ cnt, float* __restrict__ stats,
                        int* __restrict__ ovcnt, int* __restrict__ ell) {
    int g = blockIdx.x * 256 + threadIdx.x;
    if (g < 81920) {
        int m = g >> 14;
        int idx = g & 16383;
        int j  = idx & 7;
        int n  = (idx >> 3) & 15;
        int q  = (idx >> 7) & 3;
        int kk = (idx >> 9) & 3;
        int nt = (idx >> 11) & 1;
        int w  = (idx >> 12) & 3;
        int k = kk * 32 + q * 8 + j;
        int c = w * 32 + nt * 16 + n;
        const float* src = (m < 3) ? (conv_w + m * 16384) : (mlp_w + (m - 3) * 16384);
        Wf[g] = f2bf(src[k * 128 + c]);
    } else if (g < 81984) {
        hsrow[g - 81920] = 0u;                   // zero pad row HS[NN]
    } else if (g < 133184) {
        cnt[g - 81984] = 0;                      // zero degree/slot counters
    } else if (g < 133952) {
        stats[g - 133184] = 0.f;                 // zero cs3+css3 (768 floats)
    } else if (g < 133968) {
        ovcnt[g - 133952] = 0;                   // zero overflow counter
    } else if (g < 533968) {
        ((int4*)ell)[g - 133968] = make_int4(NN, NN, NN, NN);   // ELL = all pads
    }
}

// ---------------- single-pass ELL build (no CSR, no scan) ----------------
__global__ void k_fill(const int* __restrict__ ei, int* __restrict__ cnt,
                       int* __restrict__ ell, int* __restrict__ ovcnt,
                       int2* __restrict__ ov) {
    int e = blockIdx.x * 256 + threadIdx.x;
    if (e < EE) {
        int s = ei[e];
        int d = ei[EE + e];
        if ((unsigned)s < (unsigned)NN && (unsigned)d < (unsigned)NN) {
            int slot = atomicAdd(&cnt[d], 1);
            if (slot < 32) {
                ell[d * 32 + slot] = s;
            } else {
                int op = atomicAdd(ovcnt, 1);
                if (op < OVCAP) ov[op] = make_int2(d, s);
            }
        }
    }
}

// ---------------- conv MFMA GEMM: HS = pro(IN) @ W * rsqrt(cnt+1) -> bf16 -------
// 32-row x 128-col blocks, 4 waves. PRO 0: IN fp32 (layer 0). PRO 1: bf16+BN+relu.
#define LSTR 136
template<int PRO>
__global__ __launch_bounds__(256) void k_gemm_conv(const void* __restrict__ INv,
                                                   const unsigned short* __restrict__ Wf,
                                                   const int* __restrict__ cnt,
                                                   const float* __restrict__ cs,
                                                   const float* __restrict__ css,
                                                   const float* __restrict__ gamma,
                                                   const float* __restrict__ beta,
                                                   unsigned short* __restrict__ OUT) {
    __shared__ unsigned short Al[32 * LSTR];    // 8.7KB
    __shared__ float bnscL[128], bnshL[128];
    const int tid = threadIdx.x;
    const int lane = tid & 63;
    const int w = tid >> 6;
    const int row0 = blockIdx.x * 32;

    if (PRO) {
        if (tid < 128) {
            const float invn = 1.f / (float)NN;
            float mean = cs[tid] * invn;
            float var = css[tid] * invn - mean * mean;
            float sc = gamma[tid] * rsqrtf(fmaxf(var, 0.f) + 1e-5f);
            bnscL[tid] = sc;
            bnshL[tid] = beta[tid] - mean * sc;
        }
        __syncthreads();
    }

    short8 bf[2][4];
    {
        const uint4* Wq = (const uint4*)Wf;
#pragma unroll
        for (int nt = 0; nt < 2; ++nt)
#pragma unroll
            for (int kk = 0; kk < 4; ++kk) {
                uint4 u = Wq[((w * 2 + nt) * 4 + kk) * 64 + lane];
                bf[nt][kk] = *(short8*)&u;
            }
    }

    // stage A: thread -> row tid>>3 (0..31), k-octant (tid&7)*16
    {
        int r = tid >> 3, ko8 = (tid & 7) * 16;
        int gr = row0 + r;
        unsigned short tmp[16];
        if (PRO == 0) {
            const float* IN = (const float*)INv;
#pragma unroll
            for (int i = 0; i < 4; ++i) {
                float4 v = make_float4(0.f, 0.f, 0.f, 0.f);
                if (gr < NN) v = *(const float4*)&IN[(size_t)gr * DD + ko8 + i * 4];
                tmp[i * 4 + 0] = f2bf(v.x); tmp[i * 4 + 1] = f2bf(v.y);
                tmp[i * 4 + 2] = f2bf(v.z); tmp[i * 4 + 3] = f2bf(v.w);
            }
        } else {
            const unsigned int* inu = (const unsigned int*)INv;
#pragma unroll
            for (int i = 0; i < 2; ++i) {
                uint4 u = make_uint4(0u, 0u, 0u, 0u);
                if (gr < NN) u = *(const uint4*)&inu[(size_t)gr * 64 + (ko8 >> 1) + i * 4];
                float2 p0 = bf2x2(u.x), p1 = bf2x2(u.y), p2 = bf2x2(u.z), p3 = bf2x2(u.w);
                float vv[8] = {p0.x, p0.y, p1.x, p1.y, p2.x, p2.y, p3.x, p3.y};
#pragma unroll
                for (int j = 0; j < 8; ++j) {
                    float t2 = fmaf(vv[j], bnscL[ko8 + i * 8 + j], bnshL[ko8 + i * 8 + j]);
                    tmp[i * 8 + j] = f2bf(fmaxf(t2, 0.f));
                }
            }
        }
#pragma unroll
        for (int j = 0; j < 2; ++j)
            *(uint4*)&Al[r * LSTR + ko8 + j * 8] = ((uint4*)tmp)[j];
    }
    __syncthreads();

    const int n = lane & 15, q = lane >> 4;
    floatx4 acc[2][2];
#pragma unroll
    for (int mt = 0; mt < 2; ++mt)
#pragma unroll
        for (int nt = 0; nt < 2; ++nt)
            acc[mt][nt] = (floatx4){0.f, 0.f, 0.f, 0.f};

#pragma unroll
    for (int kk = 0; kk < 4; ++kk) {
        int ko = kk * 32 + q * 8;
#pragma unroll
        for (int mt = 0; mt < 2; ++mt) {
            short8 a = *(const short8*)&Al[(mt * 16 + n) * LSTR + ko];
            acc[mt][0] = __builtin_amdgcn_mfma_f32_16x16x32_bf16(a, bf[0][kk], acc[mt][0], 0, 0, 0);
            acc[mt][1] = __builtin_amdgcn_mfma_f32_16x16x32_bf16(a, bf[1][kk], acc[mt][1], 0, 0, 0);
        }
    }

#pragma unroll
    for (int mt = 0; mt < 2; ++mt) {
#pragma unroll
        for (int reg = 0; reg < 4; ++reg) {
            int r = row0 + mt * 16 + q * 4 + reg;
            if (r < NN) {
                float sc = rsqrtf((float)cnt[r] + 1.0f);
                OUT[(size_t)r * DD + w * 32 + n]      = f2bf(acc[mt][0][reg] * sc);
                OUT[(size_t)r * DD + w * 32 + 16 + n] = f2bf(acc[mt][1][reg] * sc);
            }
        }
    }
}

// ---------------- fused MLP + head (bf16 input, BN no relu), 32-row blocks ------
__global__ __launch_bounds__(256) void k_mlp_head(const unsigned int* __restrict__ INu,
                                                  const unsigned short* __restrict__ Wf4,
                                                  const unsigned short* __restrict__ Wf5,
                                                  const float* __restrict__ b4,
                                                  const float* __restrict__ b5,
                                                  const float* __restrict__ cs,
                                                  const float* __restrict__ css,
                                                  const float* __restrict__ gamma,
                                                  const float* __restrict__ beta,
                                                  const float* __restrict__ ow,
                                                  const float* __restrict__ ob,
                                                  float* __restrict__ out) {
    __shared__ unsigned short Al[32 * LSTR];
    __shared__ float bnscL[128], bnshL[128];
    __shared__ float redH[4][32];
    const int tid = threadIdx.x;
    const int lane = tid & 63;
    const int w = tid >> 6;
    const int row0 = blockIdx.x * 32;
    const int n = lane & 15, q = lane >> 4;

    if (tid < 128) {
        const float invn = 1.f / (float)NN;
        float mean = cs[tid] * invn;
        float var = css[tid] * invn - mean * mean;
        float sc = gamma[tid] * rsqrtf(fmaxf(var, 0.f) + 1e-5f);
        bnscL[tid] = sc;
        bnshL[tid] = beta[tid] - mean * sc;
    }
    __syncthreads();

    {
        int r = tid >> 3, ko8 = (tid & 7) * 16;
        int gr = row0 + r;
        unsigned short tmp[16];
#pragma unroll
        for (int i = 0; i < 2; ++i) {
            uint4 u = make_uint4(0u, 0u, 0u, 0u);
            if (gr < NN) u = *(const uint4*)&INu[(size_t)gr * 64 + (ko8 >> 1) + i * 4];
            float2 p0 = bf2x2(u.x), p1 = bf2x2(u.y), p2 = bf2x2(u.z), p3 = bf2x2(u.w);
            float vv[8] = {p0.x, p0.y, p1.x, p1.y, p2.x, p2.y, p3.x, p3.y};
#pragma unroll
            for (int j = 0; j < 8; ++j) {
                float t2 = fmaf(vv[j], bnscL[ko8 + i * 8 + j], bnshL[ko8 + i * 8 + j]);
                tmp[i * 8 + j] = f2bf(t2);
            }
        }
#pragma unroll
        for (int j = 0; j < 2; ++j)
            *(uint4*)&Al[r * LSTR + ko8 + j * 8] = ((uint4*)tmp)[j];
    }
    __syncthreads();

    floatx4 acc[2][2];
#pragma unroll
    for (int mt = 0; mt < 2; ++mt)
#pragma unroll
        for (int nt = 0; nt < 2; ++nt)
            acc[mt][nt] = (floatx4){0.f, 0.f, 0.f, 0.f};
    {
        const uint4* Wq = (const uint4*)Wf4;
#pragma unroll
        for (int kk = 0; kk < 4; ++kk) {
            uint4 u0 = Wq[((w * 2 + 0) * 4 + kk) * 64 + lane];
            uint4 u1 = Wq[((w * 2 + 1) * 4 + kk) * 64 + lane];
            int ko = kk * 32 + q * 8;
#pragma unroll
            for (int mt = 0; mt < 2; ++mt) {
                short8 a = *(const short8*)&Al[(mt * 16 + n) * LSTR + ko];
                acc[mt][0] = __builtin_amdgcn_mfma_f32_16x16x32_bf16(a, *(short8*)&u0, acc[mt][0], 0, 0, 0);
                acc[mt][1] = __builtin_amdgcn_mfma_f32_16x16x32_bf16(a, *(short8*)&u1, acc[mt][1], 0, 0, 0);
            }
        }
    }
    __syncthreads();

    {
        float b0c = b4[w * 32 + n], b1c = b4[w * 32 + 16 + n];
#pragma unroll
        for (int mt = 0; mt < 2; ++mt) {
#pragma unroll
            for (int reg = 0; reg < 4; ++reg) {
                int r = mt * 16 + q * 4 + reg;
                Al[r * LSTR + w * 32 + n]      = f2bf(fmaxf(acc[mt][0][reg] + b0c, 0.f));
                Al[r * LSTR + w * 32 + 16 + n] = f2bf(fmaxf(acc[mt][1][reg] + b1c, 0.f));
            }
        }
    }
    __syncthreads();

#pragma unroll
    for (int mt = 0; mt < 2; ++mt)
#pragma unroll
        for (int nt = 0; nt < 2; ++nt)
            acc[mt][nt] = (floatx4){0.f, 0.f, 0.f, 0.f};
    {
        const uint4* Wq = (const uint4*)Wf5;
#pragma unroll
        for (int kk = 0; kk < 4; ++kk) {
            uint4 u0 = Wq[((w * 2 + 0) * 4 + kk) * 64 + lane];
            uint4 u1 = Wq[((w * 2 + 1) * 4 + kk) * 64 + lane];
            int ko = kk * 32 + q * 8;
#pragma unroll
            for (int mt = 0; mt < 2; ++mt) {
                short8 a = *(const short8*)&Al[(mt * 16 + n) * LSTR + ko];
                acc[mt][0] = __builtin_amdgcn_mfma_f32_16x16x32_bf16(a, *(short8*)&u0, acc[mt][0], 0, 0, 0);
                acc[mt][1] = __builtin_amdgcn_mfma_f32_16x16x32_bf16(a, *(short8*)&u1, acc[mt][1], 0, 0, 0);
            }
        }
    }
    {
        float b0c = b5[w * 32 + n], b1c = b5[w * 32 + 16 + n];
        float w0c = ow[w * 32 + n], w1c = ow[w * 32 + 16 + n];
#pragma unroll
        for (int mt = 0; mt < 2; ++mt) {
#pragma unroll
            for (int reg = 0; reg < 4; ++reg) {
                float h0 = fmaxf(acc[mt][0][reg] + b0c, 0.f);
                float h1 = fmaxf(acc[mt][1][reg] + b1c, 0.f);
                float p = fmaf(h0, w0c, h1 * w1c);
                p += __shfl_xor(p, 1);
                p += __shfl_xor(p, 2);
                p += __shfl_xor(p, 4);
                p += __shfl_xor(p, 8);
                if (n == 0) redH[w][mt * 16 + q * 4 + reg] = p;
            }
        }
        __syncthreads();
        if (tid < 32) {
            int r = row0 + tid;
            if (r < NN) {
                float z = (redH[0][tid] + redH[1][tid]) + (redH[2][tid] + redH[3][tid]) + ob[0];
                out[r] = 1.f / (1.f + expf(-z));
            }
        }
    }
}
#undef LSTR

// ---------------- gather: ELL (always) + overflow list for deg>32, bf16 out -----
template<int RELU>
__global__ __launch_bounds__(256) void k_gather(const int* __restrict__ cnt,
                                                const int* __restrict__ ell,
                                                const int2* __restrict__ ov,
                                                const int* __restrict__ ovcnt,
                                                const uint4* __restrict__ HSq,
                                                const float* __restrict__ bias,
                                                unsigned short* __restrict__ OUT,
                                                float* __restrict__ colsum,
                                                float* __restrict__ colsumsq) {
    const int tid = threadIdx.x;
    const int lane = tid & 63;
    const int wid = tid >> 6;
    const int c = lane & 15;
    const int jj = lane >> 4;
    const int gwave = blockIdx.x * 4 + wid;
    const int oc = min(*ovcnt, OVCAP);

    float4 bia0 = ((const float4*)bias)[2 * c];
    float4 bia1 = ((const float4*)bias)[2 * c + 1];
    float sum[8], sq[8];
#pragma unroll
    for (int t = 0; t < 8; ++t) { sum[t] = 0.f; sq[t] = 0.f; }

    for (int r = gwave; r < NN; r += 8192) {
        int d = cnt[r];
        float a[8];
#pragma unroll
        for (int t = 0; t < 8; ++t) a[t] = 0.f;

        if (jj == 0) {   // self loop
            uint4 u = HSq[(size_t)r * 16 + c];
            float2 p0 = bf2x2(u.x), p1 = bf2x2(u.y), p2 = bf2x2(u.z), p3 = bf2x2(u.w);
            a[0] += p0.x; a[1] += p0.y; a[2] += p1.x; a[3] += p1.y;
            a[4] += p2.x; a[5] += p2.y; a[6] += p3.x; a[7] += p3.y;
        }

        // branch-free 32-slot ELL read (pads -> zero row NN)
        {
            const int4* e4 = (const int4*)(ell + r * 32);
            int4 ia = e4[jj];
            int4 ib = e4[jj + 4];
            uint4 v0 = HSq[(size_t)ia.x * 16 + c];
            uint4 v1 = HSq[(size_t)ia.y * 16 + c];
            uint4 v2 = HSq[(size_t)ia.z * 16 + c];
            uint4 v3 = HSq[(size_t)ia.w * 16 + c];
            uint4 v4 = HSq[(size_t)ib.x * 16 + c];
            uint4 v5 = HSq[(size_t)ib.y * 16 + c];
            uint4 v6 = HSq[(size_t)ib.z * 16 + c];
            uint4 v7 = HSq[(size_t)ib.w * 16 + c];
            uint4 vs[8] = {v0, v1, v2, v3, v4, v5, v6, v7};
#pragma unroll
            for (int t = 0; t < 8; ++t) {
                float2 p0 = bf2x2(vs[t].x), p1 = bf2x2(vs[t].y);
                float2 p2 = bf2x2(vs[t].z), p3 = bf2x2(vs[t].w);
                a[0] += p0.x; a[1] += p0.y; a[2] += p1.x; a[3] += p1.y;
                a[4] += p2.x; a[5] += p2.y; a[6] += p3.x; a[7] += p3.y;
            }
        }

        if (d > 32) {   // rare heavy row: scan tiny overflow list (wave-uniform)
            for (int t = 0; t < oc; ++t) {
                int2 e = ov[t];
                if (jj == 0 && e.x == r) {
                    uint4 v = HSq[(size_t)e.y * 16 + c];
                    float2 p0 = bf2x2(v.x), p1 = bf2x2(v.y), p2 = bf2x2(v.z), p3 = bf2x2(v.w);
                    a[0] += p0.x; a[1] += p0.y; a[2] += p1.x; a[3] += p1.y;
                    a[4] += p2.x; a[5] += p2.y; a[6] += p3.x; a[7] += p3.y;
                }
            }
        }

#pragma unroll
        for (int t = 0; t < 8; ++t) {
            a[t] += __shfl_xor(a[t], 16);
            a[t] += __shfl_xor(a[t], 32);
        }

        if (jj == 0) {
            float dr = rsqrtf((float)d + 1.0f);
            float v[8];
            v[0] = fmaf(dr, a[0], bia0.x); v[1] = fmaf(dr, a[1], bia0.y);
            v[2] = fmaf(dr, a[2], bia0.z); v[3] = fmaf(dr, a[3], bia0.w);
            v[4] = fmaf(dr, a[4], bia1.x); v[5] = fmaf(dr, a[5], bia1.y);
            v[6] = fmaf(dr, a[6], bia1.z); v[7] = fmaf(dr, a[7], bia1.w);
            if (RELU) {
#pragma unroll
                for (int t = 0; t < 8; ++t) v[t] = fmaxf(v[t], 0.f);
            }
            unsigned int p[4];
#pragma unroll
            for (int t = 0; t < 4; ++t)
                p[t] = (unsigned int)f2bf(v[2 * t]) | ((unsigned int)f2bf(v[2 * t + 1]) << 16);
            *(uint4*)&OUT[(size_t)r * DD + c * 8] = make_uint4(p[0], p[1], p[2], p[3]);
#pragma unroll
            for (int t = 0; t < 8; ++t) { sum[t] += v[t]; sq[t] += v[t] * v[t]; }
        }
    }

    __shared__ float redS[4][16][8];
    __shared__ float redQ[4][16][8];
    if (jj == 0) {
#pragma unroll
        for (int t = 0; t < 8; ++t) { redS[wid][c][t] = sum[t]; redQ[wid][c][t] = sq[t]; }
    }
    __syncthreads();
    if (tid < 128) {
        int ci = tid >> 3, ct = tid & 7;
        float S = (redS[0][ci][ct] + redS[1][ci][ct]) + (redS[2][ci][ct] + redS[3][ci][ct]);
        float Q = (redQ[0][ci][ct] + redQ[1][ci][ct]) + (redQ[2][ci][ct] + redQ[3][ci][ct]);
        atomicAdd(&colsum[tid], S);
        atomicAdd(&colsumsq[tid], Q);
    }
}

extern "C" void kernel_launch(void* const* d_in, const int* in_sizes, int n_in,
                              void* d_out, int out_size, void* d_ws, size_t ws_size,
                              hipStream_t stream) {
    const float* x      = (const float*)d_in[0];
    const int*   ei     = (const int*)d_in[1];
    const float* conv_w = (const float*)d_in[2];
    const float* conv_b = (const float*)d_in[3];
    const float* bn_g   = (const float*)d_in[4];
    const float* bn_b   = (const float*)d_in[5];
    const float* mlp_w  = (const float*)d_in[6];
    const float* mlp_b  = (const float*)d_in[7];
    const float* out_w  = (const float*)d_in[8];
    const float* out_b  = (const float*)d_in[9];
    float* out = (float*)d_out;

    const size_t ND4 = (size_t)NN * DD * 4;   // 25,600,000 B
    char* ws = (char*)d_ws;
    size_t off = 0;
    unsigned short* B0 = (unsigned short*)(ws + off); off += ND4 / 2;        // bf16 features
    unsigned short* B1b = (unsigned short*)(ws + off); off += ND4 / 2 + 256; // bf16 HS + pad row
    int*   cnt     = (int*)  (ws + off); off += 204800;             // degree/slot counters
    float* cs3     = (float*)(ws + off); off += 3 * 512;
    float* css3    = (float*)(ws + off); off += 3 * 512;
    int*   ovcnt   = (int*)  (ws + off); off += 64;
    int2*  ov      = (int2*) (ws + off); off += OVCAP * 8;          // 64KB overflow list
    unsigned short* Wfb = (unsigned short*)(ws + off); off += 5 * 16384 * 2;
    int*   ell     = (int*)  (ws + off); off += (size_t)NN * 32 * 4;  // 6.4MB
    // total ≈ 33.3 MB

    const int gemm_grid = (NN + 31) / 32;     // 1563 blocks, ~6.1/CU
    const int gather_grid = 2048;             // 8192 waves

    // wprep: weights (fragment order) + ELL all-pad init + zero cnt/stats/ovcnt
    k_wprep<<<2086, 256, 0, stream>>>(conv_w, mlp_w, Wfb,
        (unsigned int*)(B1b + (size_t)NN * DD), cnt, cs3, ovcnt, ell);

    // one-pass ELL build
    k_fill<<<(EE + 255) / 256, 256, 0, stream>>>(ei, cnt, ell, ovcnt, ov);

    // ---- layer 0 ----
    k_gemm_conv<0><<<gemm_grid, 256, 0, stream>>>(x, Wfb, cnt,
        nullptr, nullptr, nullptr, nullptr, B1b);
    k_gather<0><<<gather_grid, 256, 0, stream>>>(cnt, ell, ov, ovcnt, (const uint4*)B1b, conv_b, B0, cs3, css3);

    // ---- layer 1 ----
    k_gemm_conv<1><<<gemm_grid, 256, 0, stream>>>(B0, Wfb + 16384, cnt,
        cs3, css3, bn_g, bn_b, B1b);
    k_gather<0><<<gather_grid, 256, 0, stream>>>(cnt, ell, ov, ovcnt, (const uint4*)B1b, conv_b + DD, B0, cs3 + 128, css3 + 128);

    // ---- layer 2 ----
    k_gemm_conv<1><<<gemm_grid, 256, 0, stream>>>(B0, Wfb + 2 * 16384, cnt,
        cs3 + 128, css3 + 128, bn_g + DD, bn_b + DD, B1b);
    k_gather<1><<<gather_grid, 256, 0, stream>>>(cnt, ell, ov, ovcnt, (const uint4*)B1b, conv_b + 2 * DD, B0, cs3 + 256, css3 + 256);

    // ---- fused MLP + head ----
    k_mlp_head<<<gemm_grid, 256, 0, stream>>>((const unsigned int*)B0, Wfb + 3 * 16384, Wfb + 4 * 16384,
        mlp_b, mlp_b + DD, cs3 + 256, css3 + 256, bn_g + DD, bn_b + DD, out_w, out_b, out);
}

// Round 20
// 381.492 us; speedup vs baseline: 1.4012x; 1.0047x over previous
//
#include <hip/hip_runtime.h>
#include <hip/hip_bf16.h>

#define NN 50000
#define EE 800000
#define DD 128
#define OVCAP 8192

typedef __attribute__((ext_vector_type(8))) short short8;
typedef __attribute__((ext_vector_type(4))) float floatx4;

__device__ __forceinline__ unsigned short f2bf(float f) {   // RNE
    unsigned int x = __float_as_uint(f);
    unsigned int r = x + 0x7fffu + ((x >> 16) & 1u);
    return (unsigned short)(r >> 16);
}
__device__ __forceinline__ float2 bf2x2(unsigned int u) {   // [lo,hi] bf16 pair
    return make_float2(__uint_as_float(u << 16), __uint_as_float(u & 0xffff0000u));
}

// ---------------- W prep (fragment order) + ELL all-pad init + all zeroing ------
__global__ void k_wprep(const float* __restrict__ conv_w, const float* __restrict__ mlp_w,
                        unsigned short* __restrict__ Wf, unsigned int* __restrict__ hsrow,
                        int* __restrict__ cnt, float* __restrict__ stats,
                        int* __restrict__ ovcnt, int* __restrict__ ell) {
    int g = blockIdx.x * 256 + threadIdx.x;
    if (g < 81920) {
        int m = g >> 14;
        int idx = g & 16383;
        int j  = idx & 7;
        int n  = (idx >> 3) & 15;
        int q  = (idx >> 7) & 3;
        int kk = (idx >> 9) & 3;
        int nt = (idx >> 11) & 1;
        int w  = (idx >> 12) & 3;
        int k = kk * 32 + q * 8 + j;
        int c = w * 32 + nt * 16 + n;
        const float* src = (m < 3) ? (conv_w + m * 16384) : (mlp_w + (m - 3) * 16384);
        Wf[g] = f2bf(src[k * 128 + c]);
    } else if (g < 81984) {
        hsrow[g - 81920] = 0u;                   // zero pad row HS[NN]
    } else if (g < 133184) {
        cnt[g - 81984] = 0;                      // zero degree/slot counters
    } else if (g < 133952) {
        stats[g - 133184] = 0.f;                 // zero cs3+css3 (768 floats)
    } else if (g < 133968) {
        ovcnt[g - 133952] = 0;                   // zero overflow counter
    } else if (g < 533968) {
        ((int4*)ell)[g - 133968] = make_int4(NN, NN, NN, NN);   // ELL = all pads
    }
}

// ---------------- single-pass ELL build (no CSR, no scan) ----------------
__global__ void k_fill(const int* __restrict__ ei, int* __restrict__ cnt,
                       int* __restrict__ ell, int* __restrict__ ovcnt,
                       int2* __restrict__ ov) {
    int e = blockIdx.x * 256 + threadIdx.x;
    if (e < EE) {
        int s = ei[e];
        int d = ei[EE + e];
        if ((unsigned)s < (unsigned)NN && (unsigned)d < (unsigned)NN) {
            int slot = atomicAdd(&cnt[d], 1);
            if (slot < 32) {
                ell[d * 32 + slot] = s;
            } else {
                int op = atomicAdd(ovcnt, 1);
                if (op < OVCAP) ov[op] = make_int2(d, s);
            }
        }
    }
}

// ---------------- conv MFMA GEMM: HS = pro(IN) @ W * rsqrt(cnt+1) -> bf16 -------
#define LSTR 136
template<int PRO>
__global__ __launch_bounds__(256) void k_gemm_conv(const void* __restrict__ INv,
                                                   const unsigned short* __restrict__ Wf,
                                                   const int* __restrict__ cnt,
                                                   const float* __restrict__ cs,
                                                   const float* __restrict__ css,
                                                   const float* __restrict__ gamma,
                                                   const float* __restrict__ beta,
                                                   unsigned short* __restrict__ OUT) {
    __shared__ unsigned short Al[32 * LSTR];    // 8.7KB
    __shared__ float bnscL[128], bnshL[128];
    const int tid = threadIdx.x;
    const int lane = tid & 63;
    const int w = tid >> 6;
    const int row0 = blockIdx.x * 32;

    if (PRO) {
        if (tid < 128) {
            const float invn = 1.f / (float)NN;
            float mean = cs[tid] * invn;
            float var = css[tid] * invn - mean * mean;
            float sc = gamma[tid] * rsqrtf(fmaxf(var, 0.f) + 1e-5f);
            bnscL[tid] = sc;
            bnshL[tid] = beta[tid] - mean * sc;
        }
        __syncthreads();
    }

    short8 bf[2][4];
    {
        const uint4* Wq = (const uint4*)Wf;
#pragma unroll
        for (int nt = 0; nt < 2; ++nt)
#pragma unroll
            for (int kk = 0; kk < 4; ++kk) {
                uint4 u = Wq[((w * 2 + nt) * 4 + kk) * 64 + lane];
                bf[nt][kk] = *(short8*)&u;
            }
    }

    // stage A: thread -> row tid>>3 (0..31), k-octant (tid&7)*16
    {
        int r = tid >> 3, ko8 = (tid & 7) * 16;
        int gr = row0 + r;
        unsigned short tmp[16];
        if (PRO == 0) {
            const float* IN = (const float*)INv;
#pragma unroll
            for (int i = 0; i < 4; ++i) {
                float4 v = make_float4(0.f, 0.f, 0.f, 0.f);
                if (gr < NN) v = *(const float4*)&IN[(size_t)gr * DD + ko8 + i * 4];
                tmp[i * 4 + 0] = f2bf(v.x); tmp[i * 4 + 1] = f2bf(v.y);
                tmp[i * 4 + 2] = f2bf(v.z); tmp[i * 4 + 3] = f2bf(v.w);
            }
        } else {
            const unsigned int* inu = (const unsigned int*)INv;
#pragma unroll
            for (int i = 0; i < 2; ++i) {
                uint4 u = make_uint4(0u, 0u, 0u, 0u);
                if (gr < NN) u = *(const uint4*)&inu[(size_t)gr * 64 + (ko8 >> 1) + i * 4];
                float2 p0 = bf2x2(u.x), p1 = bf2x2(u.y), p2 = bf2x2(u.z), p3 = bf2x2(u.w);
                float vv[8] = {p0.x, p0.y, p1.x, p1.y, p2.x, p2.y, p3.x, p3.y};
#pragma unroll
                for (int j = 0; j < 8; ++j) {
                    float t2 = fmaf(vv[j], bnscL[ko8 + i * 8 + j], bnshL[ko8 + i * 8 + j]);
                    tmp[i * 8 + j] = f2bf(fmaxf(t2, 0.f));
                }
            }
        }
#pragma unroll
        for (int j = 0; j < 2; ++j)
            *(uint4*)&Al[r * LSTR + ko8 + j * 8] = ((uint4*)tmp)[j];
    }
    __syncthreads();

    const int n = lane & 15, q = lane >> 4;
    floatx4 acc[2][2];
#pragma unroll
    for (int mt = 0; mt < 2; ++mt)
#pragma unroll
        for (int nt = 0; nt < 2; ++nt)
            acc[mt][nt] = (floatx4){0.f, 0.f, 0.f, 0.f};

#pragma unroll
    for (int kk = 0; kk < 4; ++kk) {
        int ko = kk * 32 + q * 8;
#pragma unroll
        for (int mt = 0; mt < 2; ++mt) {
            short8 a = *(const short8*)&Al[(mt * 16 + n) * LSTR + ko];
            acc[mt][0] = __builtin_amdgcn_mfma_f32_16x16x32_bf16(a, bf[0][kk], acc[mt][0], 0, 0, 0);
            acc[mt][1] = __builtin_amdgcn_mfma_f32_16x16x32_bf16(a, bf[1][kk], acc[mt][1], 0, 0, 0);
        }
    }

#pragma unroll
    for (int mt = 0; mt < 2; ++mt) {
#pragma unroll
        for (int reg = 0; reg < 4; ++reg) {
            int r = row0 + mt * 16 + q * 4 + reg;
            if (r < NN) {
                float sc = rsqrtf((float)cnt[r] + 1.0f);
                OUT[(size_t)r * DD + w * 32 + n]      = f2bf(acc[mt][0][reg] * sc);
                OUT[(size_t)r * DD + w * 32 + 16 + n] = f2bf(acc[mt][1][reg] * sc);
            }
        }
    }
}

// ---------------- fused MLP + head (bf16 input, BN no relu), 32-row blocks ------
__global__ __launch_bounds__(256) void k_mlp_head(const unsigned int* __restrict__ INu,
                                                  const unsigned short* __restrict__ Wf4,
                                                  const unsigned short* __restrict__ Wf5,
                                                  const float* __restrict__ b4,
                                                  const float* __restrict__ b5,
                                                  const float* __restrict__ cs,
                                                  const float* __restrict__ css,
                                                  const float* __restrict__ gamma,
                                                  const float* __restrict__ beta,
                                                  const float* __restrict__ ow,
                                                  const float* __restrict__ ob,
                                                  float* __restrict__ out) {
    __shared__ unsigned short Al[32 * LSTR];
    __shared__ float bnscL[128], bnshL[128];
    __shared__ float redH[4][32];
    const int tid = threadIdx.x;
    const int lane = tid & 63;
    const int w = tid >> 6;
    const int row0 = blockIdx.x * 32;
    const int n = lane & 15, q = lane >> 4;

    if (tid < 128) {
        const float invn = 1.f / (float)NN;
        float mean = cs[tid] * invn;
        float var = css[tid] * invn - mean * mean;
        float sc = gamma[tid] * rsqrtf(fmaxf(var, 0.f) + 1e-5f);
        bnscL[tid] = sc;
        bnshL[tid] = beta[tid] - mean * sc;
    }
    __syncthreads();

    {
        int r = tid >> 3, ko8 = (tid & 7) * 16;
        int gr = row0 + r;
        unsigned short tmp[16];
#pragma unroll
        for (int i = 0; i < 2; ++i) {
            uint4 u = make_uint4(0u, 0u, 0u, 0u);
            if (gr < NN) u = *(const uint4*)&INu[(size_t)gr * 64 + (ko8 >> 1) + i * 4];
            float2 p0 = bf2x2(u.x), p1 = bf2x2(u.y), p2 = bf2x2(u.z), p3 = bf2x2(u.w);
            float vv[8] = {p0.x, p0.y, p1.x, p1.y, p2.x, p2.y, p3.x, p3.y};
#pragma unroll
            for (int j = 0; j < 8; ++j) {
                float t2 = fmaf(vv[j], bnscL[ko8 + i * 8 + j], bnshL[ko8 + i * 8 + j]);
                tmp[i * 8 + j] = f2bf(t2);
            }
        }
#pragma unroll
        for (int j = 0; j < 2; ++j)
            *(uint4*)&Al[r * LSTR + ko8 + j * 8] = ((uint4*)tmp)[j];
    }
    __syncthreads();

    floatx4 acc[2][2];
#pragma unroll
    for (int mt = 0; mt < 2; ++mt)
#pragma unroll
        for (int nt = 0; nt < 2; ++nt)
            acc[mt][nt] = (floatx4){0.f, 0.f, 0.f, 0.f};
    {
        const uint4* Wq = (const uint4*)Wf4;
#pragma unroll
        for (int kk = 0; kk < 4; ++kk) {
            uint4 u0 = Wq[((w * 2 + 0) * 4 + kk) * 64 + lane];
            uint4 u1 = Wq[((w * 2 + 1) * 4 + kk) * 64 + lane];
            int ko = kk * 32 + q * 8;
#pragma unroll
            for (int mt = 0; mt < 2; ++mt) {
                short8 a = *(const short8*)&Al[(mt * 16 + n) * LSTR + ko];
                acc[mt][0] = __builtin_amdgcn_mfma_f32_16x16x32_bf16(a, *(short8*)&u0, acc[mt][0], 0, 0, 0);
                acc[mt][1] = __builtin_amdgcn_mfma_f32_16x16x32_bf16(a, *(short8*)&u1, acc[mt][1], 0, 0, 0);
            }
        }
    }
    __syncthreads();

    {
        float b0c = b4[w * 32 + n], b1c = b4[w * 32 + 16 + n];
#pragma unroll
        for (int mt = 0; mt < 2; ++mt) {
#pragma unroll
            for (int reg = 0; reg < 4; ++reg) {
                int r = mt * 16 + q * 4 + reg;
                Al[r * LSTR + w * 32 + n]      = f2bf(fmaxf(acc[mt][0][reg] + b0c, 0.f));
                Al[r * LSTR + w * 32 + 16 + n] = f2bf(fmaxf(acc[mt][1][reg] + b1c, 0.f));
            }
        }
    }
    __syncthreads();

#pragma unroll
    for (int mt = 0; mt < 2; ++mt)
#pragma unroll
        for (int nt = 0; nt < 2; ++nt)
            acc[mt][nt] = (floatx4){0.f, 0.f, 0.f, 0.f};
    {
        const uint4* Wq = (const uint4*)Wf5;
#pragma unroll
        for (int kk = 0; kk < 4; ++kk) {
            uint4 u0 = Wq[((w * 2 + 0) * 4 + kk) * 64 + lane];
            uint4 u1 = Wq[((w * 2 + 1) * 4 + kk) * 64 + lane];
            int ko = kk * 32 + q * 8;
#pragma unroll
            for (int mt = 0; mt < 2; ++mt) {
                short8 a = *(const short8*)&Al[(mt * 16 + n) * LSTR + ko];
                acc[mt][0] = __builtin_amdgcn_mfma_f32_16x16x32_bf16(a, *(short8*)&u0, acc[mt][0], 0, 0, 0);
                acc[mt][1] = __builtin_amdgcn_mfma_f32_16x16x32_bf16(a, *(short8*)&u1, acc[mt][1], 0, 0, 0);
            }
        }
    }
    {
        float b0c = b5[w * 32 + n], b1c = b5[w * 32 + 16 + n];
        float w0c = ow[w * 32 + n], w1c = ow[w * 32 + 16 + n];
#pragma unroll
        for (int mt = 0; mt < 2; ++mt) {
#pragma unroll
            for (int reg = 0; reg < 4; ++reg) {
                float h0 = fmaxf(acc[mt][0][reg] + b0c, 0.f);
                float h1 = fmaxf(acc[mt][1][reg] + b1c, 0.f);
                float p = fmaf(h0, w0c, h1 * w1c);
                p += __shfl_xor(p, 1);
                p += __shfl_xor(p, 2);
                p += __shfl_xor(p, 4);
                p += __shfl_xor(p, 8);
                if (n == 0) redH[w][mt * 16 + q * 4 + reg] = p;
            }
        }
        __syncthreads();
        if (tid < 32) {
            int r = row0 + tid;
            if (r < NN) {
                float z = (redH[0][tid] + redH[1][tid]) + (redH[2][tid] + redH[3][tid]) + ob[0];
                out[r] = 1.f / (1.f + expf(-z));
            }
        }
    }
}
#undef LSTR

// ---------------- gather: ELL (always) + overflow list for deg>32, bf16 out -----
template<int RELU>
__global__ __launch_bounds__(256) void k_gather(const int* __restrict__ cnt,
                                                const int* __restrict__ ell,
                                                const int2* __restrict__ ov,
                                                const int* __restrict__ ovcnt,
                                                const uint4* __restrict__ HSq,
                                                const float* __restrict__ bias,
                                                unsigned short* __restrict__ OUT,
                                                float* __restrict__ colsum,
                                                float* __restrict__ colsumsq) {
    const int tid = threadIdx.x;
    const int lane = tid & 63;
    const int wid = tid >> 6;
    const int c = lane & 15;
    const int jj = lane >> 4;
    const int gwave = blockIdx.x * 4 + wid;
    const int oc = min(*ovcnt, OVCAP);

    float4 bia0 = ((const float4*)bias)[2 * c];
    float4 bia1 = ((const float4*)bias)[2 * c + 1];
    float sum[8], sq[8];
#pragma unroll
    for (int t = 0; t < 8; ++t) { sum[t] = 0.f; sq[t] = 0.f; }

    for (int r = gwave; r < NN; r += 8192) {
        int d = cnt[r];
        float a[8];
#pragma unroll
        for (int t = 0; t < 8; ++t) a[t] = 0.f;

        if (jj == 0) {   // self loop
            uint4 u = HSq[(size_t)r * 16 + c];
            float2 p0 = bf2x2(u.x), p1 = bf2x2(u.y), p2 = bf2x2(u.z), p3 = bf2x2(u.w);
            a[0] += p0.x; a[1] += p0.y; a[2] += p1.x; a[3] += p1.y;
            a[4] += p2.x; a[5] += p2.y; a[6] += p3.x; a[7] += p3.y;
        }

        // branch-free 32-slot ELL read (pads -> zero row NN)
        {
            const int4* e4 = (const int4*)(ell + r * 32);
            int4 ia = e4[jj];
            int4 ib = e4[jj + 4];
            uint4 v0 = HSq[(size_t)ia.x * 16 + c];
            uint4 v1 = HSq[(size_t)ia.y * 16 + c];
            uint4 v2 = HSq[(size_t)ia.z * 16 + c];
            uint4 v3 = HSq[(size_t)ia.w * 16 + c];
            uint4 v4 = HSq[(size_t)ib.x * 16 + c];
            uint4 v5 = HSq[(size_t)ib.y * 16 + c];
            uint4 v6 = HSq[(size_t)ib.z * 16 + c];
            uint4 v7 = HSq[(size_t)ib.w * 16 + c];
            uint4 vs[8] = {v0, v1, v2, v3, v4, v5, v6, v7};
#pragma unroll
            for (int t = 0; t < 8; ++t) {
                float2 p0 = bf2x2(vs[t].x), p1 = bf2x2(vs[t].y);
                float2 p2 = bf2x2(vs[t].z), p3 = bf2x2(vs[t].w);
                a[0] += p0.x; a[1] += p0.y; a[2] += p1.x; a[3] += p1.y;
                a[4] += p2.x; a[5] += p2.y; a[6] += p3.x; a[7] += p3.y;
            }
        }

        if (d > 32) {   // rare heavy row: scan tiny overflow list (wave-uniform)
            for (int t = 0; t < oc; ++t) {
                int2 e = ov[t];
                if (jj == 0 && e.x == r) {
                    uint4 v = HSq[(size_t)e.y * 16 + c];
                    float2 p0 = bf2x2(v.x), p1 = bf2x2(v.y), p2 = bf2x2(v.z), p3 = bf2x2(v.w);
                    a[0] += p0.x; a[1] += p0.y; a[2] += p1.x; a[3] += p1.y;
                    a[4] += p2.x; a[5] += p2.y; a[6] += p3.x; a[7] += p3.y;
                }
            }
        }

#pragma unroll
        for (int t = 0; t < 8; ++t) {
            a[t] += __shfl_xor(a[t], 16);
            a[t] += __shfl_xor(a[t], 32);
        }

        if (jj == 0) {
            float dr = rsqrtf((float)d + 1.0f);
            float v[8];
            v[0] = fmaf(dr, a[0], bia0.x); v[1] = fmaf(dr, a[1], bia0.y);
            v[2] = fmaf(dr, a[2], bia0.z); v[3] = fmaf(dr, a[3], bia0.w);
            v[4] = fmaf(dr, a[4], bia1.x); v[5] = fmaf(dr, a[5], bia1.y);
            v[6] = fmaf(dr, a[6], bia1.z); v[7] = fmaf(dr, a[7], bia1.w);
            if (RELU) {
#pragma unroll
                for (int t = 0; t < 8; ++t) v[t] = fmaxf(v[t], 0.f);
            }
            unsigned int p[4];
#pragma unroll
            for (int t = 0; t < 4; ++t)
                p[t] = (unsigned int)f2bf(v[2 * t]) | ((unsigned int)f2bf(v[2 * t + 1]) << 16);
            *(uint4*)&OUT[(size_t)r * DD + c * 8] = make_uint4(p[0], p[1], p[2], p[3]);
#pragma unroll
            for (int t = 0; t < 8; ++t) { sum[t] += v[t]; sq[t] += v[t] * v[t]; }
        }
    }

    __shared__ float redS[4][16][8];
    __shared__ float redQ[4][16][8];
    if (jj == 0) {
#pragma unroll
        for (int t = 0; t < 8; ++t) { redS[wid][c][t] = sum[t]; redQ[wid][c][t] = sq[t]; }
    }
    __syncthreads();
    if (tid < 128) {
        int ci = tid >> 3, ct = tid & 7;
        float S = (redS[0][ci][ct] + redS[1][ci][ct]) + (redS[2][ci][ct] + redS[3][ci][ct]);
        float Q = (redQ[0][ci][ct] + redQ[1][ci][ct]) + (redQ[2][ci][ct] + redQ[3][ci][ct]);
        atomicAdd(&colsum[tid], S);
        atomicAdd(&colsumsq[tid], Q);
    }
}

extern "C" void kernel_launch(void* const* d_in, const int* in_sizes, int n_in,
                              void* d_out, int out_size, void* d_ws, size_t ws_size,
                              hipStream_t stream) {
    const float* x      = (const float*)d_in[0];
    const int*   ei     = (const int*)d_in[1];
    const float* conv_w = (const float*)d_in[2];
    const float* conv_b = (const float*)d_in[3];
    const float* bn_g   = (const float*)d_in[4];
    const float* bn_b   = (const float*)d_in[5];
    const float* mlp_w  = (const float*)d_in[6];
    const float* mlp_b  = (const float*)d_in[7];
    const float* out_w  = (const float*)d_in[8];
    const float* out_b  = (const float*)d_in[9];
    float* out = (float*)d_out;

    const size_t ND4 = (size_t)NN * DD * 4;   // 25,600,000 B
    char* ws = (char*)d_ws;
    size_t off = 0;
    unsigned short* B0 = (unsigned short*)(ws + off); off += ND4 / 2;        // bf16 features
    unsigned short* B1b = (unsigned short*)(ws + off); off += ND4 / 2 + 256; // bf16 HS + pad row
    int*   cnt     = (int*)  (ws + off); off += 204800;             // degree/slot counters
    float* cs3     = (float*)(ws + off); off += 3 * 512;
    float* css3    = (float*)(ws + off); off += 3 * 512;
    int*   ovcnt   = (int*)  (ws + off); off += 64;
    int2*  ov      = (int2*) (ws + off); off += OVCAP * 8;          // 64KB overflow list
    unsigned short* Wfb = (unsigned short*)(ws + off); off += 5 * 16384 * 2;
    int*   ell     = (int*)  (ws + off); off += (size_t)NN * 32 * 4;  // 6.4MB
    // total ≈ 33.3 MB

    const int gemm_grid = (NN + 31) / 32;     // 1563 blocks, ~6.1/CU
    const int gather_grid = 2048;             // 8192 waves

    // wprep: weights (fragment order) + ELL all-pad init + zero cnt/stats/ovcnt
    k_wprep<<<2086, 256, 0, stream>>>(conv_w, mlp_w, Wfb,
        (unsigned int*)(B1b + (size_t)NN * DD), cnt, cs3, ovcnt, ell);

    // one-pass ELL build
    k_fill<<<(EE + 255) / 256, 256, 0, stream>>>(ei, cnt, ell, ovcnt, ov);

    // ---- layer 0 ----
    k_gemm_conv<0><<<gemm_grid, 256, 0, stream>>>(x, Wfb, cnt,
        nullptr, nullptr, nullptr, nullptr, B1b);
    k_gather<0><<<gather_grid, 256, 0, stream>>>(cnt, ell, ov, ovcnt, (const uint4*)B1b, conv_b, B0, cs3, css3);

    // ---- layer 1 ----
    k_gemm_conv<1><<<gemm_grid, 256, 0, stream>>>(B0, Wfb + 16384, cnt,
        cs3, css3, bn_g, bn_b, B1b);
    k_gather<0><<<gather_grid, 256, 0, stream>>>(cnt, ell, ov, ovcnt, (const uint4*)B1b, conv_b + DD, B0, cs3 + 128, css3 + 128);

    // ---- layer 2 ----
    k_gemm_conv<1><<<gemm_grid, 256, 0, stream>>>(B0, Wfb + 2 * 16384, cnt,
        cs3 + 128, css3 + 128, bn_g + DD, bn_b + DD, B1b);
    k_gather<1><<<gather_grid, 256, 0, stream>>>(cnt, ell, ov, ovcnt, (const uint4*)B1b, conv_b + 2 * DD, B0, cs3 + 256, css3 + 256);

    // ---- fused MLP + head ----
    k_mlp_head<<<gemm_grid, 256, 0, stream>>>((const unsigned int*)B0, Wfb + 3 * 16384, Wfb + 4 * 16384,
        mlp_b, mlp_b + DD, cs3 + 256, css3 + 256, bn_g + DD, bn_b + DD, out_w, out_b, out);
}